// Round 5
// baseline (2155.311 us; speedup 1.0000x reference)
//
#include <hip/hip_runtime.h>
#include <hip/hip_bf16.h>

#define EPS 1e-5f

typedef _Float16 half_t;
typedef __attribute__((ext_vector_type(8))) _Float16 h16x8;
typedef __attribute__((ext_vector_type(4))) _Float16 h16x4;
typedef __attribute__((ext_vector_type(4))) float f32x4;

__device__ __forceinline__ float relu_f(float x) { return x > 0.f ? x : 0.f; }

// ---------------- workspace layout (float units) ----------------
#define OFF_Y1   0
#define OFF_Y2   17743872
#define OFF_Y3   22179840
#define OFF_Y4   23408640
#define OFF_ST   23715840
#define OFF_WHL  23718912
// aliases inside y1 region (y1 dead after conv2):
#define OFF_A    0
#define OFF_BV   3276800
#define OFF_XG   6553600

// ---------------- prep: zero stats + cast g_w2..4 to f16, swizzled to A-frag lane order ----
// o = (mtile*8+ks)*512 + quad*128 + l15*8 + j  -> wave reads 1KB contiguous per (mtile,ks).
__global__ __launch_bounds__(256) void k_prep(const float* w2, const float* w3,
                                              const float* w4, half_t* whl, float* stats) {
    int idx = blockIdx.x * 256 + threadIdx.x;     // grid exact: 768*256 = 3*65536
    if (idx < 3072) stats[idx] = 0.f;
    int l = idx >> 16, e = idx & 65535;
    const float* w = (l == 0) ? w2 : (l == 1) ? w3 : w4;
    float v = w[e];
    int c = e >> 8, k = e & 255;
    int o = ((c >> 4) * 8 + (k >> 5)) * 512 + ((k >> 3) & 3) * 128 + (c & 15) * 8 + (k & 7);
    whl[l * 65536 + o] = (half_t)v;
}

// ---------------- conv1: 3->24 ch, 75->38, stride2 pad1, 2 images/thread ------------------
// R4: y1 layout now [img][pixel(1444)][ch(24)] f16 (channel-inner, 48B per pixel) so stores
// are 3x h16x8 (16B) per image instead of 24 scalar 2B stores (G13: scalar f16 ~2-2.5x).
__global__ __launch_bounds__(256, 2) void k_conv1(const float* img, const float* w,
                                                  const float* bias, half_t* y1, float* ostats) {
    __shared__ float wl[648], bl[24], red[4][48];
    int tid = threadIdx.x;
    if (tid < 24) bl[tid] = bias[tid];
    for (int i = tid; i < 648; i += 256) wl[i] = w[i];
    __syncthreads();
    int idx = blockIdx.x * 256 + tid;      // 1444*256 = 256*1444 exact (image-pairs)
    int b2 = idx / 1444, rem = idx % 1444;
    int b0 = b2 * 2;
    int oh = rem / 38, ow = rem % 38;
    float acc0[24], acc1[24];
#pragma unroll
    for (int o = 0; o < 24; ++o) { acc0[o] = bl[o]; acc1[o] = bl[o]; }
    for (int ic = 0; ic < 3; ++ic) {
        float p0[9], p1[9];
#pragma unroll
        for (int kh = 0; kh < 3; ++kh) {
            int ih = oh * 2 - 1 + kh;
#pragma unroll
            for (int kw = 0; kw < 3; ++kw) {
                int iw = ow * 2 - 1 + kw;
                bool ok = (unsigned)ih < 75u && (unsigned)iw < 75u;
                p0[kh * 3 + kw] = ok ? img[((b0 * 3 + ic) * 75 + ih) * 75 + iw] : 0.f;
                p1[kh * 3 + kw] = ok ? img[(((b0 + 1) * 3 + ic) * 75 + ih) * 75 + iw] : 0.f;
            }
        }
#pragma unroll
        for (int o = 0; o < 24; ++o)
#pragma unroll
            for (int t = 0; t < 9; ++t) {
                float wv = wl[(o * 3 + ic) * 9 + t];
                acc0[o] += wv * p0[t];
                acc1[o] += wv * p1[t];
            }
    }
#pragma unroll
    for (int o = 0; o < 24; ++o) { acc0[o] = relu_f(acc0[o]); acc1[o] = relu_f(acc1[o]); }
#pragma unroll
    for (int g = 0; g < 3; ++g) {
        h16x8 a, c;
#pragma unroll
        for (int j = 0; j < 8; ++j) { a[j] = (half_t)acc0[g * 8 + j]; c[j] = (half_t)acc1[g * 8 + j]; }
        *(h16x8*)&y1[((long)(b0) * 1444 + rem) * 24 + g * 8] = a;
        *(h16x8*)&y1[((long)(b0 + 1) * 1444 + rem) * 24 + g * 8] = c;
    }
    int wave = tid >> 6;
#pragma unroll
    for (int o = 0; o < 24; ++o) {
        float v = acc0[o] + acc1[o];
        float v2 = acc0[o] * acc0[o] + acc1[o] * acc1[o];
#pragma unroll
        for (int off = 1; off < 64; off <<= 1) { v += __shfl_xor(v, off); v2 += __shfl_xor(v2, off); }
        if ((tid & 63) == 0) { red[wave][o] = v; red[wave][24 + o] = v2; }
    }
    __syncthreads();
    if (tid < 48)
        atomicAdd(&ostats[(blockIdx.x & 15) * 48 + tid],
                  red[0][tid] + red[1][tid] + red[2][tid] + red[3][tid]);
}

// ---------------- conv2: 24->24, 38->19, 2 images/thread; channel-inner f16 in -------------
// R4: reads 24ch per tap as 3x h16x8 (16B) per image (was 432 scalar 2B loads/thread);
// weights re-staged to [tap][o][ic] so inner reads are ds_read_b128 (1296 vs 5184 ds ops);
// sc/sh hoisted to registers. Padding stays zero in BN-output domain (p=0 when !ok).
__global__ __launch_bounds__(256, 2) void k_conv2(const half_t* yin, const float* w,
                                                  const float* bias, const float* instats,
                                                  const float* bng, const float* bnb,
                                                  float* yout, float* ostats) {
    __shared__ float wl[5184], bl[24], scs[24], shs[24], red[4][48];
    int tid = threadIdx.x;
    if (tid < 24) {
        float s = 0.f, s2 = 0.f;
#pragma unroll
        for (int k = 0; k < 16; ++k) { s += instats[k * 48 + tid]; s2 += instats[k * 48 + 24 + tid]; }
        float mu = s * (1.f / 739328.f);
        float var = s2 * (1.f / 739328.f) - mu * mu;
        float sca = bng[tid] * rsqrtf(var + EPS);
        scs[tid] = sca; shs[tid] = bnb[tid] - mu * sca;
        bl[tid] = bias[tid];
    }
    for (int i = tid; i < 5184; i += 256) {
        int t = i / 576, r = i % 576;
        int o = r / 24, ic = r % 24;
        wl[i] = w[(o * 24 + ic) * 9 + t];      // [tap][o][ic]
    }
    __syncthreads();
    float scr[24], shr[24];
#pragma unroll
    for (int ic = 0; ic < 24; ++ic) { scr[ic] = scs[ic]; shr[ic] = shs[ic]; }
    int idx = blockIdx.x * 256 + tid;      // 361*256 = 256*361 exact (image-pairs)
    int b2 = idx / 361, rem = idx % 361;
    int b0 = b2 * 2;
    int oh = rem / 19, ow = rem % 19;
    float acc0[24], acc1[24];
#pragma unroll
    for (int o = 0; o < 24; ++o) { acc0[o] = bl[o]; acc1[o] = bl[o]; }
#pragma unroll
    for (int kh = 0; kh < 3; ++kh) {
        int ih = oh * 2 - 1 + kh;
#pragma unroll
        for (int kw = 0; kw < 3; ++kw) {
            int iw = ow * 2 - 1 + kw;
            bool ok = (unsigned)ih < 38u && (unsigned)iw < 38u;
            float p0[24], p1[24];
            if (ok) {
                long px = (long)ih * 38 + iw;
                const half_t* s0 = &yin[((long)b0 * 1444 + px) * 24];
                const half_t* s1 = &yin[((long)(b0 + 1) * 1444 + px) * 24];
                h16x8 v00 = *(const h16x8*)&s0[0], v01 = *(const h16x8*)&s0[8], v02 = *(const h16x8*)&s0[16];
                h16x8 v10 = *(const h16x8*)&s1[0], v11 = *(const h16x8*)&s1[8], v12 = *(const h16x8*)&s1[16];
#pragma unroll
                for (int j = 0; j < 8; ++j) {
                    p0[j]      = (float)v00[j] * scr[j]      + shr[j];
                    p0[8 + j]  = (float)v01[j] * scr[8 + j]  + shr[8 + j];
                    p0[16 + j] = (float)v02[j] * scr[16 + j] + shr[16 + j];
                    p1[j]      = (float)v10[j] * scr[j]      + shr[j];
                    p1[8 + j]  = (float)v11[j] * scr[8 + j]  + shr[8 + j];
                    p1[16 + j] = (float)v12[j] * scr[16 + j] + shr[16 + j];
                }
            } else {
#pragma unroll
                for (int ic = 0; ic < 24; ++ic) { p0[ic] = 0.f; p1[ic] = 0.f; }
            }
            const float* wt = &wl[(kh * 3 + kw) * 576];
#pragma unroll
            for (int o = 0; o < 24; ++o) {
                const float4* w4 = (const float4*)&wt[o * 24];
#pragma unroll
                for (int q = 0; q < 6; ++q) {
                    float4 wv = w4[q];
                    acc0[o] += wv.x * p0[q * 4] + wv.y * p0[q * 4 + 1] + wv.z * p0[q * 4 + 2] + wv.w * p0[q * 4 + 3];
                    acc1[o] += wv.x * p1[q * 4] + wv.y * p1[q * 4 + 1] + wv.z * p1[q * 4 + 2] + wv.w * p1[q * 4 + 3];
                }
            }
        }
    }
    int wave = tid >> 6;
#pragma unroll
    for (int o = 0; o < 24; ++o) {
        acc0[o] = relu_f(acc0[o]);
        acc1[o] = relu_f(acc1[o]);
        yout[(b0 * 24 + o) * 361 + rem] = acc0[o];
        yout[((b0 + 1) * 24 + o) * 361 + rem] = acc1[o];
        float v = acc0[o] + acc1[o];
        float v2 = acc0[o] * acc0[o] + acc1[o] * acc1[o];
#pragma unroll
        for (int off = 1; off < 64; off <<= 1) { v += __shfl_xor(v, off); v2 += __shfl_xor(v2, off); }
        if ((tid & 63) == 0) { red[wave][o] = v; red[wave][24 + o] = v2; }
    }
    __syncthreads();
    if (tid < 48)
        atomicAdd(&ostats[(blockIdx.x & 15) * 48 + tid],
                  red[0][tid] + red[1][tid] + red[2][tid] + red[3][tid]);
}

// ---------------- conv3/4: 24->24, stride2 pad1; in-BN folded; fused out-stats ------------
__global__ __launch_bounds__(256) void k_conv(const float* yin, const float* w,
                                              const float* bias, const float* instats,
                                              const float* bng, const float* bnb,
                                              float* yout, float* ostats,
                                              int Hin, int Hout, float invN) {
    __shared__ float wl[5184], bl[24], sc[24], sh[24], red[4][48];
    int tid = threadIdx.x;
    if (tid < 24) {
        float s = 0.f, s2 = 0.f;
#pragma unroll
        for (int k = 0; k < 16; ++k) { s += instats[k * 48 + tid]; s2 += instats[k * 48 + 24 + tid]; }
        float mu = s * invN;
        float var = s2 * invN - mu * mu;
        float sca = bng[tid] * rsqrtf(var + EPS);
        sc[tid] = sca; sh[tid] = bnb[tid] - mu * sca;
        bl[tid] = bias[tid];
    }
    for (int i = tid; i < 5184; i += 256) wl[i] = w[i];
    __syncthreads();
    int idx = blockIdx.x * 256 + tid;      // grids exact
    int HWo = Hout * Hout;
    int b = idx / HWo, rem = idx % HWo;
    int oh = rem / Hout, ow = rem % Hout;
    float acc[24];
#pragma unroll
    for (int o = 0; o < 24; ++o) acc[o] = bl[o];
    for (int ic = 0; ic < 24; ++ic) {
        float patch[9];
        float scc = sc[ic], shc = sh[ic];
#pragma unroll
        for (int kh = 0; kh < 3; ++kh) {
            int ih = oh * 2 - 1 + kh;
#pragma unroll
            for (int kw = 0; kw < 3; ++kw) {
                int iw = ow * 2 - 1 + kw;
                bool ok = (unsigned)ih < (unsigned)Hin && (unsigned)iw < (unsigned)Hin;
                patch[kh * 3 + kw] = ok ? yin[((b * 24 + ic) * Hin + ih) * Hin + iw] * scc + shc : 0.f;
            }
        }
#pragma unroll
        for (int o = 0; o < 24; ++o)
#pragma unroll
            for (int t = 0; t < 9; ++t) acc[o] += wl[(o * 24 + ic) * 9 + t] * patch[t];
    }
    int wave = tid >> 6;
#pragma unroll
    for (int o = 0; o < 24; ++o) {
        acc[o] = relu_f(acc[o]);
        yout[(b * 24 + o) * HWo + rem] = acc[o];
        float v = acc[o], v2 = v * v;
#pragma unroll
        for (int off = 1; off < 64; off <<= 1) { v += __shfl_xor(v, off); v2 += __shfl_xor(v2, off); }
        if ((tid & 63) == 0) { red[wave][o] = v; red[wave][24 + o] = v2; }
    }
    __syncthreads();
    if (tid < 48)
        atomicAdd(&ostats[(blockIdx.x & 15) * 48 + tid],
                  red[0][tid] + red[1][tid] + red[2][tid] + red[3][tid]);
}

// ---------------- objects: bn4 + coords once into LDS, project through split g_w1 ----------
__global__ __launch_bounds__(256) void k_obj(const float* y4, const float* qst,
                                             const float* w1, const float* b1,
                                             const float* instats, const float* bng,
                                             const float* bnb, float* A, float* Bv, float* xg) {
    int b = blockIdx.x, tid = threadIdx.x;
    __shared__ float w1l[16128];
    __shared__ float objs[25][28];
    __shared__ float sc[24], sh[24], q[11];
    xg[b * 256 + tid] = 0.f;
    for (int i = tid; i < 16128; i += 256) w1l[i] = w1[i];
    if (tid < 24) {
        float s = 0.f, s2 = 0.f;
#pragma unroll
        for (int k = 0; k < 16; ++k) { s += instats[k * 48 + tid]; s2 += instats[k * 48 + 24 + tid]; }
        float mu = s * (1.f / 12800.f);
        float var = s2 * (1.f / 12800.f) - mu * mu;
        float sca = bng[tid] * rsqrtf(var + EPS);
        sc[tid] = sca; sh[tid] = bnb[tid] - mu * sca;
    }
    if (tid < 11) q[tid] = qst[b * 11 + tid];
    __syncthreads();
    for (int i = tid; i < 600; i += 256) {
        int c = i / 25, p = i % 25;
        objs[p][c] = y4[b * 600 + i] * sc[c] + sh[c];
    }
    if (tid < 25) { objs[tid][24] = ((tid / 5) - 2) * 0.5f; objs[tid][25] = ((tid % 5) - 2) * 0.5f; }
    __syncthreads();
    float wr[63];
#pragma unroll
    for (int k = 0; k < 63; ++k) wr[k] = w1l[tid * 63 + k];
    float qdot = b1[tid];
#pragma unroll
    for (int j = 0; j < 11; ++j) qdot += wr[52 + j] * q[j];
#pragma unroll 1
    for (int p = 0; p < 25; ++p) {
        float a = 0.f, bv = qdot;
#pragma unroll
        for (int k = 0; k < 26; ++k) { a += wr[k] * objs[p][k]; bv += wr[26 + k] * objs[p][k]; }
        A[(b * 25 + p) * 256 + tid] = a;
        Bv[(b * 25 + p) * 256 + tid] = bv;
    }
}

// ---------------- fused g-MLP v4: 64-row tile, 4 waves, 4 blocks/CU, setprio ---------------
// R4 measured: 154.8us, MfmaUtil 38.9 (= exactly the 60us of MFMA work / 155us). Plateaued
// across 3 structural variants (154-165); kept as best. MFMA-busy is pinned at the work
// demand, so further k_g gains need an 8-phase-class rebuild (deferred; k_g is 25% of total).
__global__ __launch_bounds__(256, 4) void k_g(const float* A, const float* Bv, const half_t* whl,
                                              const float* gb2, const float* gb3,
                                              const float* gb4, float* xg) {
    __shared__ alignas(16) half_t h[64 * 264];
    __shared__ float biasL[3][256];
    int tid = threadIdx.x;
    int lb = (blockIdx.x & 7) * 640 + (blockIdx.x >> 3);   // XCD-contiguous (5120%8==0)
    int b = lb / 10, t = lb % 10;
    int r0 = t * 64;
    int rmax = 625 - r0; if (rmax > 64) rmax = 64;
    biasL[0][tid] = gb2[tid];
    biasL[1][tid] = gb3[tid];
    biasL[2][tid] = gb4[tid];
    const float* Ab = A + b * 6400;
    const float* Bb = Bv + b * 6400;
#pragma unroll
    for (int it = 0; it < 16; ++it) {
        int r = it * 4 + (tid >> 6);                       // wave-uniform row
        int rs = __builtin_amdgcn_readfirstlane(r);
        int pr = r0 + rs; if (pr > 624) pr = 624;          // clamp; masked at final sum
        int i = pr % 25, j = pr / 25;                      // scalar div/mod
        int c4 = (tid & 63) << 2;
        float4 av = *(const float4*)&Ab[i * 256 + c4];
        float4 bv = *(const float4*)&Bb[j * 256 + c4];
        h16x4 hv = {(half_t)relu_f(av.x + bv.x), (half_t)relu_f(av.y + bv.y),
                    (half_t)relu_f(av.z + bv.z), (half_t)relu_f(av.w + bv.w)};
        *(h16x4*)&h[r * 264 + c4] = hv;
    }
    __syncthreads();
    int cg = tid >> 6, lane = tid & 63;                    // 4 waves = 4 channel-groups
    int quad = lane >> 4, l15 = lane & 15;
    const half_t* hr = h + l15 * 264;                      // this lane's row base
    const half_t* Wl = whl + (cg * 4) * 8 * 512 + lane * 8;  // wave's W base (mi=0, ks=0)
#pragma unroll 1
    for (int layer = 0; layer < 3; ++layer) {
        const half_t* W = Wl + layer * 65536;
        f32x4 acc[4][4];
#pragma unroll
        for (int mi = 0; mi < 4; ++mi)
#pragma unroll
            for (int nt = 0; nt < 4; ++nt) acc[mi][nt] = (f32x4){0.f, 0.f, 0.f, 0.f};
        // prologue: ks=0 operands in flight
        h16x8 aw0 = *(const h16x8*)&W[0 * 4096];
        h16x8 aw1 = *(const h16x8*)&W[1 * 4096];
        h16x8 aw2 = *(const h16x8*)&W[2 * 4096];
        h16x8 aw3 = *(const h16x8*)&W[3 * 4096];
        h16x8 bh0 = *(const h16x8*)&hr[0 * 4224 + quad * 8];
        h16x8 bh1 = *(const h16x8*)&hr[1 * 4224 + quad * 8];
#pragma unroll 2
        for (int ks = 0; ks < 8; ++ks) {
            int ko = ks * 32 + quad * 8;
            int ksn = (ks + 1) & 7;                 // wrap: harmless redundant load at ks=7
            int kon = ksn * 32 + quad * 8;
            // this-iter second half (covered by nt=0,1 MFMA burst):
            h16x8 bh2 = *(const h16x8*)&hr[2 * 4224 + ko];
            h16x8 bh3 = *(const h16x8*)&hr[3 * 4224 + ko];
            // next-iter W (covered by full 16-MFMA burst):
            h16x8 an0 = *(const h16x8*)&W[0 * 4096 + ksn * 512];
            h16x8 an1 = *(const h16x8*)&W[1 * 4096 + ksn * 512];
            h16x8 an2 = *(const h16x8*)&W[2 * 4096 + ksn * 512];
            h16x8 an3 = *(const h16x8*)&W[3 * 4096 + ksn * 512];
            __builtin_amdgcn_s_setprio(1);
            acc[0][0] = __builtin_amdgcn_mfma_f32_16x16x32_f16(aw0, bh0, acc[0][0], 0, 0, 0);
            acc[1][0] = __builtin_amdgcn_mfma_f32_16x16x32_f16(aw1, bh0, acc[1][0], 0, 0, 0);
            acc[2][0] = __builtin_amdgcn_mfma_f32_16x16x32_f16(aw2, bh0, acc[2][0], 0, 0, 0);
            acc[3][0] = __builtin_amdgcn_mfma_f32_16x16x32_f16(aw3, bh0, acc[3][0], 0, 0, 0);
            acc[0][1] = __builtin_amdgcn_mfma_f32_16x16x32_f16(aw0, bh1, acc[0][1], 0, 0, 0);
            acc[1][1] = __builtin_amdgcn_mfma_f32_16x16x32_f16(aw1, bh1, acc[1][1], 0, 0, 0);
            acc[2][1] = __builtin_amdgcn_mfma_f32_16x16x32_f16(aw2, bh1, acc[2][1], 0, 0, 0);
            acc[3][1] = __builtin_amdgcn_mfma_f32_16x16x32_f16(aw3, bh1, acc[3][1], 0, 0, 0);
            // next-iter first half (covered by nt=2,3 MFMA burst):
            h16x8 bn0 = *(const h16x8*)&hr[0 * 4224 + kon];
            h16x8 bn1 = *(const h16x8*)&hr[1 * 4224 + kon];
            acc[0][2] = __builtin_amdgcn_mfma_f32_16x16x32_f16(aw0, bh2, acc[0][2], 0, 0, 0);
            acc[1][2] = __builtin_amdgcn_mfma_f32_16x16x32_f16(aw1, bh2, acc[1][2], 0, 0, 0);
            acc[2][2] = __builtin_amdgcn_mfma_f32_16x16x32_f16(aw2, bh2, acc[2][2], 0, 0, 0);
            acc[3][2] = __builtin_amdgcn_mfma_f32_16x16x32_f16(aw3, bh2, acc[3][2], 0, 0, 0);
            acc[0][3] = __builtin_amdgcn_mfma_f32_16x16x32_f16(aw0, bh3, acc[0][3], 0, 0, 0);
            acc[1][3] = __builtin_amdgcn_mfma_f32_16x16x32_f16(aw1, bh3, acc[1][3], 0, 0, 0);
            acc[2][3] = __builtin_amdgcn_mfma_f32_16x16x32_f16(aw2, bh3, acc[2][3], 0, 0, 0);
            acc[3][3] = __builtin_amdgcn_mfma_f32_16x16x32_f16(aw3, bh3, acc[3][3], 0, 0, 0);
            __builtin_amdgcn_s_setprio(0);
            aw0 = an0; aw1 = an1; aw2 = an2; aw3 = an3;
            bh0 = bn0; bh1 = bn1;
        }
        __syncthreads();   // all reads of h done; safe to overwrite
        if (layer < 2) {
#pragma unroll
            for (int mi = 0; mi < 4; ++mi) {
                int c0 = cg * 64 + mi * 16 + quad * 4;
#pragma unroll
                for (int nt = 0; nt < 4; ++nt) {
                    int row = nt * 16 + l15;
                    h16x4 hv;
#pragma unroll
                    for (int v = 0; v < 4; ++v)
                        hv[v] = (half_t)relu_f(acc[mi][nt][v] + biasL[layer][c0 + v]);
                    *(h16x4*)&h[row * 264 + c0] = hv;
                }
            }
            __syncthreads();
        } else {
#pragma unroll
            for (int mi = 0; mi < 4; ++mi) {
                int c0 = cg * 64 + mi * 16 + quad * 4;
#pragma unroll
                for (int v = 0; v < 4; ++v) {
                    float s = 0.f;
#pragma unroll
                    for (int nt = 0; nt < 4; ++nt) {
                        int row = nt * 16 + l15;
                        float x = relu_f(acc[mi][nt][v] + biasL[2][c0 + v]);
                        if (row < rmax) s += x;
                    }
                    s += __shfl_xor(s, 1);
                    s += __shfl_xor(s, 2);
                    s += __shfl_xor(s, 4);
                    s += __shfl_xor(s, 8);
                    if (l15 == 0) atomicAdd(&xg[b * 256 + c0 + v], s);
                }
            }
        }
    }
}

// ---------------- f-MLP + log_softmax (2 batches per block) ----------------
__global__ __launch_bounds__(256) void k_f(const float* xg, const float* fw1, const float* fb1,
                                           const float* fw2, const float* fb2,
                                           const float* fw3, const float* fb3, float* out) {
    int b0 = blockIdx.x * 2, tid = threadIdx.x;
    __shared__ float xb[2][256], h1[2][256], l10[2][10], red[2];
    xb[0][tid] = xg[b0 * 256 + tid];
    xb[1][tid] = xg[(b0 + 1) * 256 + tid];
    __syncthreads();
    float s0 = fb1[tid], s1 = s0;
    {
        const float4* wr = (const float4*)&fw1[tid * 256];
        const float4* x0 = (const float4*)xb[0];
        const float4* x1 = (const float4*)xb[1];
#pragma unroll 8
        for (int k = 0; k < 64; ++k) {
            float4 w = wr[k], a = x0[k], c = x1[k];
            s0 += w.x * a.x + w.y * a.y + w.z * a.z + w.w * a.w;
            s1 += w.x * c.x + w.y * c.y + w.z * c.z + w.w * c.w;
        }
    }
    h1[0][tid] = relu_f(s0);
    h1[1][tid] = relu_f(s1);
    __syncthreads();
    s0 = fb2[tid]; s1 = s0;
    {
        const float4* wr = (const float4*)&fw2[tid * 256];
        const float4* x0 = (const float4*)h1[0];
        const float4* x1 = (const float4*)h1[1];
#pragma unroll 8
        for (int k = 0; k < 64; ++k) {
            float4 w = wr[k], a = x0[k], c = x1[k];
            s0 += w.x * a.x + w.y * a.y + w.z * a.z + w.w * a.w;
            s1 += w.x * c.x + w.y * c.y + w.z * c.z + w.w * c.w;
        }
    }
    __syncthreads();
    xb[0][tid] = relu_f(s0);
    xb[1][tid] = relu_f(s1);
    __syncthreads();
    if (tid < 20) {
        int bb = tid / 10, o = tid % 10;
        float v = fb3[o];
        const float4* wr = (const float4*)&fw3[o * 256];
        const float4* hv = (const float4*)xb[bb];
#pragma unroll 8
        for (int k = 0; k < 64; ++k) {
            float4 w = wr[k], x = hv[k];
            v += w.x * x.x + w.y * x.y + w.z * x.z + w.w * x.w;
        }
        l10[bb][o] = v;
    }
    __syncthreads();
    if (tid < 2) {
        float m = l10[tid][0];
        for (int i = 1; i < 10; ++i) m = fmaxf(m, l10[tid][i]);
        float e = 0.f;
        for (int i = 0; i < 10; ++i) e += expf(l10[tid][i] - m);
        red[tid] = m + logf(e);
    }
    __syncthreads();
    if (tid < 20) {
        int bb = tid / 10, o = tid % 10;
        out[(b0 + bb) * 10 + o] = l10[bb][o] - red[bb];
    }
}

extern "C" void kernel_launch(void* const* d_in, const int* in_sizes, int n_in,
                              void* d_out, int out_size, void* d_ws, size_t ws_size,
                              hipStream_t stream) {
    const float* img = (const float*)d_in[0];
    const float* qst = (const float*)d_in[1];
    const float* cw[4] = {(const float*)d_in[2], (const float*)d_in[6],
                          (const float*)d_in[10], (const float*)d_in[14]};
    const float* cb[4] = {(const float*)d_in[3], (const float*)d_in[7],
                          (const float*)d_in[11], (const float*)d_in[15]};
    const float* bg[4] = {(const float*)d_in[4], (const float*)d_in[8],
                          (const float*)d_in[12], (const float*)d_in[16]};
    const float* bb[4] = {(const float*)d_in[5], (const float*)d_in[9],
                          (const float*)d_in[13], (const float*)d_in[17]};
    const float* gw1 = (const float*)d_in[18];
    const float* gb1 = (const float*)d_in[19];
    const float* gw2 = (const float*)d_in[20];
    const float* gb2 = (const float*)d_in[21];
    const float* gw3 = (const float*)d_in[22];
    const float* gb3 = (const float*)d_in[23];
    const float* gw4 = (const float*)d_in[24];
    const float* gb4 = (const float*)d_in[25];
    const float* fw1 = (const float*)d_in[26];
    const float* fb1 = (const float*)d_in[27];
    const float* fw2 = (const float*)d_in[28];
    const float* fb2 = (const float*)d_in[29];
    const float* fw3 = (const float*)d_in[30];
    const float* fb3 = (const float*)d_in[31];

    float* ws = (float*)d_ws;
    half_t* y1 = (half_t*)(ws + OFF_Y1);   // f16 intermediate, [img][pix][24ch]
    float* y2 = ws + OFF_Y2;
    float* y3 = ws + OFF_Y3;
    float* y4 = ws + OFF_Y4;
    float* st = ws + OFF_ST;            // 4 layers * 16 slots * 48
    half_t* whl = (half_t*)(ws + OFF_WHL);
    float* A = ws + OFF_A;              // aliases y1 (dead after conv2)
    float* Bv = ws + OFF_BV;
    float* xg = ws + OFF_XG;
    float* out = (float*)d_out;

    k_prep<<<768, 256, 0, stream>>>(gw2, gw3, gw4, whl, st);
    k_conv1<<<1444, 256, 0, stream>>>(img, cw[0], cb[0], y1, st + 0 * 768);
    k_conv2<<<361, 256, 0, stream>>>(y1, cw[1], cb[1], st + 0 * 768, bg[0], bb[0], y2,
                                     st + 1 * 768);
    k_conv<<<200, 256, 0, stream>>>(y2, cw[2], cb[2], st + 1 * 768, bg[1], bb[1], y3,
                                    st + 2 * 768, 19, 10, 1.f / 184832.f);
    k_conv<<<50, 256, 0, stream>>>(y3, cw[3], cb[3], st + 2 * 768, bg[2], bb[2], y4,
                                   st + 3 * 768, 10, 5, 1.f / 51200.f);
    k_obj<<<512, 256, 0, stream>>>(y4, qst, gw1, gb1, st + 3 * 768, bg[3], bb[3], A, Bv, xg);
    k_g<<<5120, 256, 0, stream>>>(A, Bv, whl, gb2, gb3, gb4, xg);
    k_f<<<256, 256, 0, stream>>>(xg, fw1, fb1, fw2, fb2, fw3, fb3, out);
}

// Round 6
// 583.151 us; speedup vs baseline: 3.6960x; 3.6960x over previous
//
#include <hip/hip_runtime.h>
#include <hip/hip_bf16.h>

#define EPS 1e-5f

typedef _Float16 half_t;
typedef __attribute__((ext_vector_type(8))) _Float16 h16x8;
typedef __attribute__((ext_vector_type(4))) _Float16 h16x4;
typedef __attribute__((ext_vector_type(4))) float f32x4;

__device__ __forceinline__ float relu_f(float x) { return x > 0.f ? x : 0.f; }

// ---------------- workspace layout (float units) ----------------
#define OFF_Y1   0
#define OFF_Y2   17743872
#define OFF_Y3   22179840
#define OFF_Y4   23408640
#define OFF_ST   23715840
#define OFF_WHL  23718912
// aliases inside y1 region (y1 dead after conv2):
#define OFF_A    0
#define OFF_BV   3276800
#define OFF_XG   6553600

// ---------------- prep: zero stats + cast g_w2..4 to f16, swizzled to A-frag lane order ----
// o = (mtile*8+ks)*512 + quad*128 + l15*8 + j  -> wave reads 1KB contiguous per (mtile,ks).
__global__ __launch_bounds__(256) void k_prep(const float* w2, const float* w3,
                                              const float* w4, half_t* whl, float* stats) {
    int idx = blockIdx.x * 256 + threadIdx.x;     // grid exact: 768*256 = 3*65536
    if (idx < 3072) stats[idx] = 0.f;
    int l = idx >> 16, e = idx & 65535;
    const float* w = (l == 0) ? w2 : (l == 1) ? w3 : w4;
    float v = w[e];
    int c = e >> 8, k = e & 255;
    int o = ((c >> 4) * 8 + (k >> 5)) * 512 + ((k >> 3) & 3) * 128 + (c & 15) * 8 + (k & 7);
    whl[l * 65536 + o] = (half_t)v;
}

// ---------------- conv1: 3->24 ch, 75->38, stride2 pad1, 2 images/thread ------------------
// R4: y1 layout [img][pixel(1444)][ch(24)] f16 (channel-inner) so stores are 3x h16x8 (16B)
// per image instead of 24 scalar 2B stores (G13).
__global__ __launch_bounds__(256, 2) void k_conv1(const float* img, const float* w,
                                                  const float* bias, half_t* y1, float* ostats) {
    __shared__ float wl[648], bl[24], red[4][48];
    int tid = threadIdx.x;
    if (tid < 24) bl[tid] = bias[tid];
    for (int i = tid; i < 648; i += 256) wl[i] = w[i];
    __syncthreads();
    int idx = blockIdx.x * 256 + tid;      // 1444*256 = 256*1444 exact (image-pairs)
    int b2 = idx / 1444, rem = idx % 1444;
    int b0 = b2 * 2;
    int oh = rem / 38, ow = rem % 38;
    float acc0[24], acc1[24];
#pragma unroll
    for (int o = 0; o < 24; ++o) { acc0[o] = bl[o]; acc1[o] = bl[o]; }
    for (int ic = 0; ic < 3; ++ic) {
        float p0[9], p1[9];
#pragma unroll
        for (int kh = 0; kh < 3; ++kh) {
            int ih = oh * 2 - 1 + kh;
#pragma unroll
            for (int kw = 0; kw < 3; ++kw) {
                int iw = ow * 2 - 1 + kw;
                bool ok = (unsigned)ih < 75u && (unsigned)iw < 75u;
                p0[kh * 3 + kw] = ok ? img[((b0 * 3 + ic) * 75 + ih) * 75 + iw] : 0.f;
                p1[kh * 3 + kw] = ok ? img[(((b0 + 1) * 3 + ic) * 75 + ih) * 75 + iw] : 0.f;
            }
        }
#pragma unroll
        for (int o = 0; o < 24; ++o)
#pragma unroll
            for (int t = 0; t < 9; ++t) {
                float wv = wl[(o * 3 + ic) * 9 + t];
                acc0[o] += wv * p0[t];
                acc1[o] += wv * p1[t];
            }
    }
#pragma unroll
    for (int o = 0; o < 24; ++o) { acc0[o] = relu_f(acc0[o]); acc1[o] = relu_f(acc1[o]); }
#pragma unroll
    for (int g = 0; g < 3; ++g) {
        h16x8 a, c;
#pragma unroll
        for (int j = 0; j < 8; ++j) { a[j] = (half_t)acc0[g * 8 + j]; c[j] = (half_t)acc1[g * 8 + j]; }
        *(h16x8*)&y1[((long)(b0) * 1444 + rem) * 24 + g * 8] = a;
        *(h16x8*)&y1[((long)(b0 + 1) * 1444 + rem) * 24 + g * 8] = c;
    }
    int wave = tid >> 6;
#pragma unroll
    for (int o = 0; o < 24; ++o) {
        float v = acc0[o] + acc1[o];
        float v2 = acc0[o] * acc0[o] + acc1[o] * acc1[o];
#pragma unroll
        for (int off = 1; off < 64; off <<= 1) { v += __shfl_xor(v, off); v2 += __shfl_xor(v2, off); }
        if ((tid & 63) == 0) { red[wave][o] = v; red[wave][24 + o] = v2; }
    }
    __syncthreads();
    if (tid < 48)
        atomicAdd(&ostats[(blockIdx.x & 15) * 48 + tid],
                  red[0][tid] + red[1][tid] + red[2][tid] + red[3][tid]);
}

// ---------------- conv2 v2: channel-inner vec loads, ic-blocked, register-budgeted ---------
// R5 post-mortem: v1 of this rewrite spilled (VGPR_Count 128, 4.2GB scratch traffic/dispatch,
// 1658us). Root cause: acc(48)+p(48)+scr/shr hoist(48)+6xh16x8(24) live > 128. v2 budget:
// ic-blocked by 8 -> only 2 h16x8 + p0[8]/p1[8] live; sc/sh stay in LDS (broadcast reads are
// free); boundary taps skipped whole (pad-zero adds nothing, semantics identical);
// launch_bounds(256) only. Est ~92 VGPR. Weight LDS is [tap][o][ic] -> float4 broadcast reads.
__global__ __launch_bounds__(256) void k_conv2(const half_t* yin, const float* w,
                                               const float* bias, const float* instats,
                                               const float* bng, const float* bnb,
                                               float* yout, float* ostats) {
    __shared__ float wl[5184], bl[24], scs[24], shs[24], red[4][48];
    int tid = threadIdx.x;
    if (tid < 24) {
        float s = 0.f, s2 = 0.f;
#pragma unroll
        for (int k = 0; k < 16; ++k) { s += instats[k * 48 + tid]; s2 += instats[k * 48 + 24 + tid]; }
        float mu = s * (1.f / 739328.f);
        float var = s2 * (1.f / 739328.f) - mu * mu;
        float sca = bng[tid] * rsqrtf(var + EPS);
        scs[tid] = sca; shs[tid] = bnb[tid] - mu * sca;
        bl[tid] = bias[tid];
    }
    for (int i = tid; i < 5184; i += 256) {
        int t = i / 576, r = i % 576;
        int o = r / 24, ic = r % 24;
        wl[i] = w[(o * 24 + ic) * 9 + t];      // [tap][o][ic]
    }
    __syncthreads();
    int idx = blockIdx.x * 256 + tid;      // 361*256 = 256*361 exact (image-pairs)
    int b2 = idx / 361, rem = idx % 361;
    int b0 = b2 * 2;
    int oh = rem / 19, ow = rem % 19;
    float acc0[24], acc1[24];
#pragma unroll
    for (int o = 0; o < 24; ++o) { acc0[o] = bl[o]; acc1[o] = bl[o]; }
#pragma unroll
    for (int kh = 0; kh < 3; ++kh) {
        int ih = oh * 2 - 1 + kh;
#pragma unroll
        for (int kw = 0; kw < 3; ++kw) {
            int iw = ow * 2 - 1 + kw;
            if ((unsigned)ih < 38u && (unsigned)iw < 38u) {
                long px = (long)ih * 38 + iw;
                const half_t* s0 = &yin[((long)b0 * 1444 + px) * 24];
                const half_t* s1 = &yin[((long)(b0 + 1) * 1444 + px) * 24];
                const float* wt = &wl[(kh * 3 + kw) * 576];
#pragma unroll
                for (int g = 0; g < 3; ++g) {
                    h16x8 v0 = *(const h16x8*)&s0[g * 8];
                    h16x8 v1 = *(const h16x8*)&s1[g * 8];
                    float p0[8], p1[8];
#pragma unroll
                    for (int j = 0; j < 8; ++j) {
                        float sc = scs[g * 8 + j], sh = shs[g * 8 + j];
                        p0[j] = (float)v0[j] * sc + sh;
                        p1[j] = (float)v1[j] * sc + sh;
                    }
#pragma unroll
                    for (int o = 0; o < 24; ++o) {
                        const float4* w4 = (const float4*)&wt[o * 24 + g * 8];
                        float4 wa = w4[0], wb = w4[1];
                        acc0[o] += wa.x * p0[0] + wa.y * p0[1] + wa.z * p0[2] + wa.w * p0[3]
                                 + wb.x * p0[4] + wb.y * p0[5] + wb.z * p0[6] + wb.w * p0[7];
                        acc1[o] += wa.x * p1[0] + wa.y * p1[1] + wa.z * p1[2] + wa.w * p1[3]
                                 + wb.x * p1[4] + wb.y * p1[5] + wb.z * p1[6] + wb.w * p1[7];
                    }
                }
            }
        }
    }
    int wave = tid >> 6;
#pragma unroll
    for (int o = 0; o < 24; ++o) {
        acc0[o] = relu_f(acc0[o]);
        acc1[o] = relu_f(acc1[o]);
        yout[(b0 * 24 + o) * 361 + rem] = acc0[o];
        yout[((b0 + 1) * 24 + o) * 361 + rem] = acc1[o];
        float v = acc0[o] + acc1[o];
        float v2 = acc0[o] * acc0[o] + acc1[o] * acc1[o];
#pragma unroll
        for (int off = 1; off < 64; off <<= 1) { v += __shfl_xor(v, off); v2 += __shfl_xor(v2, off); }
        if ((tid & 63) == 0) { red[wave][o] = v; red[wave][24 + o] = v2; }
    }
    __syncthreads();
    if (tid < 48)
        atomicAdd(&ostats[(blockIdx.x & 15) * 48 + tid],
                  red[0][tid] + red[1][tid] + red[2][tid] + red[3][tid]);
}

// ---------------- conv3/4: 24->24, stride2 pad1; in-BN folded; fused out-stats ------------
__global__ __launch_bounds__(256) void k_conv(const float* yin, const float* w,
                                              const float* bias, const float* instats,
                                              const float* bng, const float* bnb,
                                              float* yout, float* ostats,
                                              int Hin, int Hout, float invN) {
    __shared__ float wl[5184], bl[24], sc[24], sh[24], red[4][48];
    int tid = threadIdx.x;
    if (tid < 24) {
        float s = 0.f, s2 = 0.f;
#pragma unroll
        for (int k = 0; k < 16; ++k) { s += instats[k * 48 + tid]; s2 += instats[k * 48 + 24 + tid]; }
        float mu = s * invN;
        float var = s2 * invN - mu * mu;
        float sca = bng[tid] * rsqrtf(var + EPS);
        sc[tid] = sca; sh[tid] = bnb[tid] - mu * sca;
        bl[tid] = bias[tid];
    }
    for (int i = tid; i < 5184; i += 256) wl[i] = w[i];
    __syncthreads();
    int idx = blockIdx.x * 256 + tid;      // grids exact
    int HWo = Hout * Hout;
    int b = idx / HWo, rem = idx % HWo;
    int oh = rem / Hout, ow = rem % Hout;
    float acc[24];
#pragma unroll
    for (int o = 0; o < 24; ++o) acc[o] = bl[o];
    for (int ic = 0; ic < 24; ++ic) {
        float patch[9];
        float scc = sc[ic], shc = sh[ic];
#pragma unroll
        for (int kh = 0; kh < 3; ++kh) {
            int ih = oh * 2 - 1 + kh;
#pragma unroll
            for (int kw = 0; kw < 3; ++kw) {
                int iw = ow * 2 - 1 + kw;
                bool ok = (unsigned)ih < (unsigned)Hin && (unsigned)iw < (unsigned)Hin;
                patch[kh * 3 + kw] = ok ? yin[((b * 24 + ic) * Hin + ih) * Hin + iw] * scc + shc : 0.f;
            }
        }
#pragma unroll
        for (int o = 0; o < 24; ++o)
#pragma unroll
            for (int t = 0; t < 9; ++t) acc[o] += wl[(o * 24 + ic) * 9 + t] * patch[t];
    }
    int wave = tid >> 6;
#pragma unroll
    for (int o = 0; o < 24; ++o) {
        acc[o] = relu_f(acc[o]);
        yout[(b * 24 + o) * HWo + rem] = acc[o];
        float v = acc[o], v2 = v * v;
#pragma unroll
        for (int off = 1; off < 64; off <<= 1) { v += __shfl_xor(v, off); v2 += __shfl_xor(v2, off); }
        if ((tid & 63) == 0) { red[wave][o] = v; red[wave][24 + o] = v2; }
    }
    __syncthreads();
    if (tid < 48)
        atomicAdd(&ostats[(blockIdx.x & 15) * 48 + tid],
                  red[0][tid] + red[1][tid] + red[2][tid] + red[3][tid]);
}

// ---------------- objects: bn4 + coords once into LDS, project through split g_w1 ----------
__global__ __launch_bounds__(256) void k_obj(const float* y4, const float* qst,
                                             const float* w1, const float* b1,
                                             const float* instats, const float* bng,
                                             const float* bnb, float* A, float* Bv, float* xg) {
    int b = blockIdx.x, tid = threadIdx.x;
    __shared__ float w1l[16128];
    __shared__ float objs[25][28];
    __shared__ float sc[24], sh[24], q[11];
    xg[b * 256 + tid] = 0.f;
    for (int i = tid; i < 16128; i += 256) w1l[i] = w1[i];
    if (tid < 24) {
        float s = 0.f, s2 = 0.f;
#pragma unroll
        for (int k = 0; k < 16; ++k) { s += instats[k * 48 + tid]; s2 += instats[k * 48 + 24 + tid]; }
        float mu = s * (1.f / 12800.f);
        float var = s2 * (1.f / 12800.f) - mu * mu;
        float sca = bng[tid] * rsqrtf(var + EPS);
        sc[tid] = sca; sh[tid] = bnb[tid] - mu * sca;
    }
    if (tid < 11) q[tid] = qst[b * 11 + tid];
    __syncthreads();
    for (int i = tid; i < 600; i += 256) {
        int c = i / 25, p = i % 25;
        objs[p][c] = y4[b * 600 + i] * sc[c] + sh[c];
    }
    if (tid < 25) { objs[tid][24] = ((tid / 5) - 2) * 0.5f; objs[tid][25] = ((tid % 5) - 2) * 0.5f; }
    __syncthreads();
    float wr[63];
#pragma unroll
    for (int k = 0; k < 63; ++k) wr[k] = w1l[tid * 63 + k];
    float qdot = b1[tid];
#pragma unroll
    for (int j = 0; j < 11; ++j) qdot += wr[52 + j] * q[j];
#pragma unroll 1
    for (int p = 0; p < 25; ++p) {
        float a = 0.f, bv = qdot;
#pragma unroll
        for (int k = 0; k < 26; ++k) { a += wr[k] * objs[p][k]; bv += wr[26 + k] * objs[p][k]; }
        A[(b * 25 + p) * 256 + tid] = a;
        Bv[(b * 25 + p) * 256 + tid] = bv;
    }
}

// ---------------- fused g-MLP v4: 64-row tile, 4 waves, 4 blocks/CU, setprio ---------------
// R4 measured: 154.8us, MfmaUtil 38.9 (= exactly the 60us of MFMA work / 155us). Plateaued
// across 3 structural variants (154-165); kept as best.
__global__ __launch_bounds__(256, 4) void k_g(const float* A, const float* Bv, const half_t* whl,
                                              const float* gb2, const float* gb3,
                                              const float* gb4, float* xg) {
    __shared__ alignas(16) half_t h[64 * 264];
    __shared__ float biasL[3][256];
    int tid = threadIdx.x;
    int lb = (blockIdx.x & 7) * 640 + (blockIdx.x >> 3);   // XCD-contiguous (5120%8==0)
    int b = lb / 10, t = lb % 10;
    int r0 = t * 64;
    int rmax = 625 - r0; if (rmax > 64) rmax = 64;
    biasL[0][tid] = gb2[tid];
    biasL[1][tid] = gb3[tid];
    biasL[2][tid] = gb4[tid];
    const float* Ab = A + b * 6400;
    const float* Bb = Bv + b * 6400;
#pragma unroll
    for (int it = 0; it < 16; ++it) {
        int r = it * 4 + (tid >> 6);                       // wave-uniform row
        int rs = __builtin_amdgcn_readfirstlane(r);
        int pr = r0 + rs; if (pr > 624) pr = 624;          // clamp; masked at final sum
        int i = pr % 25, j = pr / 25;                      // scalar div/mod
        int c4 = (tid & 63) << 2;
        float4 av = *(const float4*)&Ab[i * 256 + c4];
        float4 bv = *(const float4*)&Bb[j * 256 + c4];
        h16x4 hv = {(half_t)relu_f(av.x + bv.x), (half_t)relu_f(av.y + bv.y),
                    (half_t)relu_f(av.z + bv.z), (half_t)relu_f(av.w + bv.w)};
        *(h16x4*)&h[r * 264 + c4] = hv;
    }
    __syncthreads();
    int cg = tid >> 6, lane = tid & 63;                    // 4 waves = 4 channel-groups
    int quad = lane >> 4, l15 = lane & 15;
    const half_t* hr = h + l15 * 264;                      // this lane's row base
    const half_t* Wl = whl + (cg * 4) * 8 * 512 + lane * 8;  // wave's W base (mi=0, ks=0)
#pragma unroll 1
    for (int layer = 0; layer < 3; ++layer) {
        const half_t* W = Wl + layer * 65536;
        f32x4 acc[4][4];
#pragma unroll
        for (int mi = 0; mi < 4; ++mi)
#pragma unroll
            for (int nt = 0; nt < 4; ++nt) acc[mi][nt] = (f32x4){0.f, 0.f, 0.f, 0.f};
        // prologue: ks=0 operands in flight
        h16x8 aw0 = *(const h16x8*)&W[0 * 4096];
        h16x8 aw1 = *(const h16x8*)&W[1 * 4096];
        h16x8 aw2 = *(const h16x8*)&W[2 * 4096];
        h16x8 aw3 = *(const h16x8*)&W[3 * 4096];
        h16x8 bh0 = *(const h16x8*)&hr[0 * 4224 + quad * 8];
        h16x8 bh1 = *(const h16x8*)&hr[1 * 4224 + quad * 8];
#pragma unroll 2
        for (int ks = 0; ks < 8; ++ks) {
            int ko = ks * 32 + quad * 8;
            int ksn = (ks + 1) & 7;                 // wrap: harmless redundant load at ks=7
            int kon = ksn * 32 + quad * 8;
            // this-iter second half (covered by nt=0,1 MFMA burst):
            h16x8 bh2 = *(const h16x8*)&hr[2 * 4224 + ko];
            h16x8 bh3 = *(const h16x8*)&hr[3 * 4224 + ko];
            // next-iter W (covered by full 16-MFMA burst):
            h16x8 an0 = *(const h16x8*)&W[0 * 4096 + ksn * 512];
            h16x8 an1 = *(const h16x8*)&W[1 * 4096 + ksn * 512];
            h16x8 an2 = *(const h16x8*)&W[2 * 4096 + ksn * 512];
            h16x8 an3 = *(const h16x8*)&W[3 * 4096 + ksn * 512];
            __builtin_amdgcn_s_setprio(1);
            acc[0][0] = __builtin_amdgcn_mfma_f32_16x16x32_f16(aw0, bh0, acc[0][0], 0, 0, 0);
            acc[1][0] = __builtin_amdgcn_mfma_f32_16x16x32_f16(aw1, bh0, acc[1][0], 0, 0, 0);
            acc[2][0] = __builtin_amdgcn_mfma_f32_16x16x32_f16(aw2, bh0, acc[2][0], 0, 0, 0);
            acc[3][0] = __builtin_amdgcn_mfma_f32_16x16x32_f16(aw3, bh0, acc[3][0], 0, 0, 0);
            acc[0][1] = __builtin_amdgcn_mfma_f32_16x16x32_f16(aw0, bh1, acc[0][1], 0, 0, 0);
            acc[1][1] = __builtin_amdgcn_mfma_f32_16x16x32_f16(aw1, bh1, acc[1][1], 0, 0, 0);
            acc[2][1] = __builtin_amdgcn_mfma_f32_16x16x32_f16(aw2, bh1, acc[2][1], 0, 0, 0);
            acc[3][1] = __builtin_amdgcn_mfma_f32_16x16x32_f16(aw3, bh1, acc[3][1], 0, 0, 0);
            // next-iter first half (covered by nt=2,3 MFMA burst):
            h16x8 bn0 = *(const h16x8*)&hr[0 * 4224 + kon];
            h16x8 bn1 = *(const h16x8*)&hr[1 * 4224 + kon];
            acc[0][2] = __builtin_amdgcn_mfma_f32_16x16x32_f16(aw0, bh2, acc[0][2], 0, 0, 0);
            acc[1][2] = __builtin_amdgcn_mfma_f32_16x16x32_f16(aw1, bh2, acc[1][2], 0, 0, 0);
            acc[2][2] = __builtin_amdgcn_mfma_f32_16x16x32_f16(aw2, bh2, acc[2][2], 0, 0, 0);
            acc[3][2] = __builtin_amdgcn_mfma_f32_16x16x32_f16(aw3, bh2, acc[3][2], 0, 0, 0);
            acc[0][3] = __builtin_amdgcn_mfma_f32_16x16x32_f16(aw0, bh3, acc[0][3], 0, 0, 0);
            acc[1][3] = __builtin_amdgcn_mfma_f32_16x16x32_f16(aw1, bh3, acc[1][3], 0, 0, 0);
            acc[2][3] = __builtin_amdgcn_mfma_f32_16x16x32_f16(aw2, bh3, acc[2][3], 0, 0, 0);
            acc[3][3] = __builtin_amdgcn_mfma_f32_16x16x32_f16(aw3, bh3, acc[3][3], 0, 0, 0);
            __builtin_amdgcn_s_setprio(0);
            aw0 = an0; aw1 = an1; aw2 = an2; aw3 = an3;
            bh0 = bn0; bh1 = bn1;
        }
        __syncthreads();   // all reads of h done; safe to overwrite
        if (layer < 2) {
#pragma unroll
            for (int mi = 0; mi < 4; ++mi) {
                int c0 = cg * 64 + mi * 16 + quad * 4;
#pragma unroll
                for (int nt = 0; nt < 4; ++nt) {
                    int row = nt * 16 + l15;
                    h16x4 hv;
#pragma unroll
                    for (int v = 0; v < 4; ++v)
                        hv[v] = (half_t)relu_f(acc[mi][nt][v] + biasL[layer][c0 + v]);
                    *(h16x4*)&h[row * 264 + c0] = hv;
                }
            }
            __syncthreads();
        } else {
#pragma unroll
            for (int mi = 0; mi < 4; ++mi) {
                int c0 = cg * 64 + mi * 16 + quad * 4;
#pragma unroll
                for (int v = 0; v < 4; ++v) {
                    float s = 0.f;
#pragma unroll
                    for (int nt = 0; nt < 4; ++nt) {
                        int row = nt * 16 + l15;
                        float x = relu_f(acc[mi][nt][v] + biasL[2][c0 + v]);
                        if (row < rmax) s += x;
                    }
                    s += __shfl_xor(s, 1);
                    s += __shfl_xor(s, 2);
                    s += __shfl_xor(s, 4);
                    s += __shfl_xor(s, 8);
                    if (l15 == 0) atomicAdd(&xg[b * 256 + c0 + v], s);
                }
            }
        }
    }
}

// ---------------- f-MLP + log_softmax (2 batches per block) ----------------
__global__ __launch_bounds__(256) void k_f(const float* xg, const float* fw1, const float* fb1,
                                           const float* fw2, const float* fb2,
                                           const float* fw3, const float* fb3, float* out) {
    int b0 = blockIdx.x * 2, tid = threadIdx.x;
    __shared__ float xb[2][256], h1[2][256], l10[2][10], red[2];
    xb[0][tid] = xg[b0 * 256 + tid];
    xb[1][tid] = xg[(b0 + 1) * 256 + tid];
    __syncthreads();
    float s0 = fb1[tid], s1 = s0;
    {
        const float4* wr = (const float4*)&fw1[tid * 256];
        const float4* x0 = (const float4*)xb[0];
        const float4* x1 = (const float4*)xb[1];
#pragma unroll 8
        for (int k = 0; k < 64; ++k) {
            float4 w = wr[k], a = x0[k], c = x1[k];
            s0 += w.x * a.x + w.y * a.y + w.z * a.z + w.w * a.w;
            s1 += w.x * c.x + w.y * c.y + w.z * c.z + w.w * c.w;
        }
    }
    h1[0][tid] = relu_f(s0);
    h1[1][tid] = relu_f(s1);
    __syncthreads();
    s0 = fb2[tid]; s1 = s0;
    {
        const float4* wr = (const float4*)&fw2[tid * 256];
        const float4* x0 = (const float4*)h1[0];
        const float4* x1 = (const float4*)h1[1];
#pragma unroll 8
        for (int k = 0; k < 64; ++k) {
            float4 w = wr[k], a = x0[k], c = x1[k];
            s0 += w.x * a.x + w.y * a.y + w.z * a.z + w.w * a.w;
            s1 += w.x * c.x + w.y * c.y + w.z * c.z + w.w * c.w;
        }
    }
    __syncthreads();
    xb[0][tid] = relu_f(s0);
    xb[1][tid] = relu_f(s1);
    __syncthreads();
    if (tid < 20) {
        int bb = tid / 10, o = tid % 10;
        float v = fb3[o];
        const float4* wr = (const float4*)&fw3[o * 256];
        const float4* hv = (const float4*)xb[bb];
#pragma unroll 8
        for (int k = 0; k < 64; ++k) {
            float4 w = wr[k], x = hv[k];
            v += w.x * x.x + w.y * x.y + w.z * x.z + w.w * x.w;
        }
        l10[bb][o] = v;
    }
    __syncthreads();
    if (tid < 2) {
        float m = l10[tid][0];
        for (int i = 1; i < 10; ++i) m = fmaxf(m, l10[tid][i]);
        float e = 0.f;
        for (int i = 0; i < 10; ++i) e += expf(l10[tid][i] - m);
        red[tid] = m + logf(e);
    }
    __syncthreads();
    if (tid < 20) {
        int bb = tid / 10, o = tid % 10;
        out[(b0 + bb) * 10 + o] = l10[bb][o] - red[bb];
    }
}

extern "C" void kernel_launch(void* const* d_in, const int* in_sizes, int n_in,
                              void* d_out, int out_size, void* d_ws, size_t ws_size,
                              hipStream_t stream) {
    const float* img = (const float*)d_in[0];
    const float* qst = (const float*)d_in[1];
    const float* cw[4] = {(const float*)d_in[2], (const float*)d_in[6],
                          (const float*)d_in[10], (const float*)d_in[14]};
    const float* cb[4] = {(const float*)d_in[3], (const float*)d_in[7],
                          (const float*)d_in[11], (const float*)d_in[15]};
    const float* bg[4] = {(const float*)d_in[4], (const float*)d_in[8],
                          (const float*)d_in[12], (const float*)d_in[16]};
    const float* bb[4] = {(const float*)d_in[5], (const float*)d_in[9],
                          (const float*)d_in[13], (const float*)d_in[17]};
    const float* gw1 = (const float*)d_in[18];
    const float* gb1 = (const float*)d_in[19];
    const float* gw2 = (const float*)d_in[20];
    const float* gb2 = (const float*)d_in[21];
    const float* gw3 = (const float*)d_in[22];
    const float* gb3 = (const float*)d_in[23];
    const float* gw4 = (const float*)d_in[24];
    const float* gb4 = (const float*)d_in[25];
    const float* fw1 = (const float*)d_in[26];
    const float* fb1 = (const float*)d_in[27];
    const float* fw2 = (const float*)d_in[28];
    const float* fb2 = (const float*)d_in[29];
    const float* fw3 = (const float*)d_in[30];
    const float* fb3 = (const float*)d_in[31];

    float* ws = (float*)d_ws;
    half_t* y1 = (half_t*)(ws + OFF_Y1);   // f16 intermediate, [img][pix][24ch]
    float* y2 = ws + OFF_Y2;
    float* y3 = ws + OFF_Y3;
    float* y4 = ws + OFF_Y4;
    float* st = ws + OFF_ST;            // 4 layers * 16 slots * 48
    half_t* whl = (half_t*)(ws + OFF_WHL);
    float* A = ws + OFF_A;              // aliases y1 (dead after conv2)
    float* Bv = ws + OFF_BV;
    float* xg = ws + OFF_XG;
    float* out = (float*)d_out;

    k_prep<<<768, 256, 0, stream>>>(gw2, gw3, gw4, whl, st);
    k_conv1<<<1444, 256, 0, stream>>>(img, cw[0], cb[0], y1, st + 0 * 768);
    k_conv2<<<361, 256, 0, stream>>>(y1, cw[1], cb[1], st + 0 * 768, bg[0], bb[0], y2,
                                     st + 1 * 768);
    k_conv<<<200, 256, 0, stream>>>(y2, cw[2], cb[2], st + 1 * 768, bg[1], bb[1], y3,
                                    st + 2 * 768, 19, 10, 1.f / 184832.f);
    k_conv<<<50, 256, 0, stream>>>(y3, cw[3], cb[3], st + 2 * 768, bg[2], bb[2], y4,
                                   st + 3 * 768, 10, 5, 1.f / 51200.f);
    k_obj<<<512, 256, 0, stream>>>(y4, qst, gw1, gb1, st + 3 * 768, bg[3], bb[3], A, Bv, xg);
    k_g<<<5120, 256, 0, stream>>>(A, Bv, whl, gb2, gb3, gb4, xg);
    k_f<<<256, 256, 0, stream>>>(xg, fw1, fb1, fw2, fb2, fw3, fb3, out);
}

// Round 7
// 521.736 us; speedup vs baseline: 4.1310x; 1.1177x over previous
//
#include <hip/hip_runtime.h>
#include <hip/hip_bf16.h>

#define EPS 1e-5f

typedef _Float16 half_t;
typedef __attribute__((ext_vector_type(8))) _Float16 h16x8;
typedef __attribute__((ext_vector_type(4))) _Float16 h16x4;
typedef __attribute__((ext_vector_type(4))) float f32x4;

__device__ __forceinline__ float relu_f(float x) { return x > 0.f ? x : 0.f; }

// ---------------- workspace layout (float units) ----------------
#define OFF_Y1   0
#define OFF_Y2   17743872
#define OFF_Y3   22179840
#define OFF_Y4   23408640
#define OFF_ST   23715840
#define OFF_WHL  23718912
// aliases inside y1 region (y1 dead after conv2):
#define OFF_A    0
#define OFF_BV   3276800
#define OFF_XG   6553600
// free hole: y1 as f16 uses only floats [0, 8871936) of its legacy region:
#define OFF_WHL2 8871936

// ---------------- prep: zero stats + cast g_w2..4 to f16, swizzled to A-frag lane order ----
// o = (mtile*8+ks)*512 + quad*128 + l15*8 + j  -> wave reads 1KB contiguous per (mtile,ks).
__global__ __launch_bounds__(256) void k_prep(const float* w2, const float* w3,
                                              const float* w4, half_t* whl, float* stats) {
    int idx = blockIdx.x * 256 + threadIdx.x;     // grid exact: 768*256 = 3*65536
    if (idx < 3072) stats[idx] = 0.f;
    int l = idx >> 16, e = idx & 65535;
    const float* w = (l == 0) ? w2 : (l == 1) ? w3 : w4;
    float v = w[e];
    int c = e >> 8, k = e & 255;
    int o = ((c >> 4) * 8 + (k >> 5)) * 512 + ((k >> 3) & 3) * 128 + (c & 15) * 8 + (k & 7);
    whl[l * 65536 + o] = (half_t)v;
}

// ---------------- prep2: conv2 weights -> B-frag layout (K=tap*24+ic pad 224, oc pad 32) ---
// offset(ntile,ks,quad,l15,j) = (ntile*7+ks)*512 + quad*128 + l15*8 + j; k=ks*32+quad*8+j.
__global__ __launch_bounds__(256) void k_prep2(const float* w2, half_t* whl2) {
    int idx = blockIdx.x * 256 + threadIdx.x;     // 28*256 = 7168 exact
    int ntile = idx / 3584, r = idx % 3584;
    int ks = r / 512, w = r % 512;
    int quad = w / 128, l15 = (w >> 3) & 15, j = w & 7;
    int k = ks * 32 + quad * 8 + j;
    int oc = ntile * 16 + l15;
    float v = 0.f;
    if (k < 216 && oc < 24) {
        int tap = k / 24, ic = k % 24;
        v = w2[(oc * 24 + ic) * 9 + tap];
    }
    whl2[idx] = (half_t)v;
}

// ---------------- conv1: 3->24 ch, 75->38, stride2 pad1, 2 images/thread ------------------
// R4: y1 layout [img][pixel(1444)][ch(24)] f16 (channel-inner) so stores are 3x h16x8 (16B)
// per image instead of 24 scalar 2B stores (G13).
__global__ __launch_bounds__(256, 2) void k_conv1(const float* img, const float* w,
                                                  const float* bias, half_t* y1, float* ostats) {
    __shared__ float wl[648], bl[24], red[4][48];
    int tid = threadIdx.x;
    if (tid < 24) bl[tid] = bias[tid];
    for (int i = tid; i < 648; i += 256) wl[i] = w[i];
    __syncthreads();
    int idx = blockIdx.x * 256 + tid;      // 1444*256 = 256*1444 exact (image-pairs)
    int b2 = idx / 1444, rem = idx % 1444;
    int b0 = b2 * 2;
    int oh = rem / 38, ow = rem % 38;
    float acc0[24], acc1[24];
#pragma unroll
    for (int o = 0; o < 24; ++o) { acc0[o] = bl[o]; acc1[o] = bl[o]; }
    for (int ic = 0; ic < 3; ++ic) {
        float p0[9], p1[9];
#pragma unroll
        for (int kh = 0; kh < 3; ++kh) {
            int ih = oh * 2 - 1 + kh;
#pragma unroll
            for (int kw = 0; kw < 3; ++kw) {
                int iw = ow * 2 - 1 + kw;
                bool ok = (unsigned)ih < 75u && (unsigned)iw < 75u;
                p0[kh * 3 + kw] = ok ? img[((b0 * 3 + ic) * 75 + ih) * 75 + iw] : 0.f;
                p1[kh * 3 + kw] = ok ? img[(((b0 + 1) * 3 + ic) * 75 + ih) * 75 + iw] : 0.f;
            }
        }
#pragma unroll
        for (int o = 0; o < 24; ++o)
#pragma unroll
            for (int t = 0; t < 9; ++t) {
                float wv = wl[(o * 3 + ic) * 9 + t];
                acc0[o] += wv * p0[t];
                acc1[o] += wv * p1[t];
            }
    }
#pragma unroll
    for (int o = 0; o < 24; ++o) { acc0[o] = relu_f(acc0[o]); acc1[o] = relu_f(acc1[o]); }
#pragma unroll
    for (int g = 0; g < 3; ++g) {
        h16x8 a, c;
#pragma unroll
        for (int j = 0; j < 8; ++j) { a[j] = (half_t)acc0[g * 8 + j]; c[j] = (half_t)acc1[g * 8 + j]; }
        *(h16x8*)&y1[((long)(b0) * 1444 + rem) * 24 + g * 8] = a;
        *(h16x8*)&y1[((long)(b0 + 1) * 1444 + rem) * 24 + g * 8] = c;
    }
    int wave = tid >> 6;
#pragma unroll
    for (int o = 0; o < 24; ++o) {
        float v = acc0[o] + acc1[o];
        float v2 = acc0[o] * acc0[o] + acc1[o] * acc1[o];
#pragma unroll
        for (int off = 1; off < 64; off <<= 1) { v += __shfl_xor(v, off); v2 += __shfl_xor(v2, off); }
        if ((tid & 63) == 0) { red[wave][o] = v; red[wave][24 + o] = v2; }
    }
    __syncthreads();
    if (tid < 48)
        atomicAdd(&ostats[(blockIdx.x & 15) * 48 + tid],
                  red[0][tid] + red[1][tid] + red[2][tid] + red[3][tid]);
}

// ---------------- conv2 v3: MFMA im2col GEMM, 1 image/block -------------------------------
// R6 theory: conv2-v2 (86us by R5 subtraction) was LDS-broadcast-bound: 1296 ds_read_b128
// weight broadcasts/thread (~36us/CU) + 96B-stride gather loads. K=216 dot products belong
// on the matrix pipe (Common-mistake #10). v3: stage BN-applied image (69KB) into LDS
// coalesced, then D[361px x 24oc] = X[px x 224] * W[224 x 32] via 16x16x32 f16 MFMA using
// k_g's verified frag conventions (A lane: l15=M, quad*8=k; D: col=l15=N, row=quad*4+v=M).
// Taps span 24=3x8 ch -> every 8-k run stays in one tap -> A-frag = ONE ds_read_b128.
// Out-of-range k/border -> zeroed LDS slot. Outputs staged to stride-369 LDS (conflict-free)
// then written contiguously (y2 linear = b*8664+i). 322 MFMA/image ~ 1.3us matrix work.
__global__ __launch_bounds__(256) void k_conv2(const half_t* yin, const half_t* whl2,
                                               const float* bias, const float* instats,
                                               const float* bng, const float* bnb,
                                               float* yout, float* ostats) {
    __shared__ half_t yL[34672];          // 38*38*24 + zero slot @34656
    __shared__ half_t wf[7168];
    __shared__ float outL[8856];          // 24 x stride 369
    __shared__ float scs[24], shs[24], bl[24], red[4][48];
    int tid = threadIdx.x;
    int b = blockIdx.x;
    if (tid < 24) {
        float s = 0.f, s2 = 0.f;
#pragma unroll
        for (int k = 0; k < 16; ++k) { s += instats[k * 48 + tid]; s2 += instats[k * 48 + 24 + tid]; }
        float mu = s * (1.f / 739328.f);
        float var = s2 * (1.f / 739328.f) - mu * mu;
        float sca = bng[tid] * rsqrtf(var + EPS);
        scs[tid] = sca; shs[tid] = bnb[tid] - mu * sca;
        bl[tid] = bias[tid];
    }
    if (tid < 16) yL[34656 + tid] = (half_t)0.f;   // zero slot (+pad)
    for (int i = tid; i < 896; i += 256)
        ((h16x8*)wf)[i] = ((const h16x8*)whl2)[i];
    __syncthreads();
    // stage image with input-BN applied (channels per 8-chunk never wrap: 24 = 3*8)
    const half_t* ybase = yin + (long)b * 34656;
    for (int i = tid; i < 4332; i += 256) {
        h16x8 v = *(const h16x8*)&ybase[i * 8];
        int ch0 = (i % 3) * 8;
        h16x8 o;
#pragma unroll
        for (int j = 0; j < 8; ++j)
            o[j] = (half_t)((float)v[j] * scs[ch0 + j] + shs[ch0 + j]);
        *(h16x8*)&yL[i * 8] = o;
    }
    __syncthreads();
    int wv = tid >> 6, lane = tid & 63, quad = lane >> 4, l15 = lane & 15;
    float bb0 = bl[l15];
    float bb1 = (l15 < 8) ? bl[16 + l15] : 0.f;
    float s0 = 0.f, q0 = 0.f, s1 = 0.f, q1 = 0.f;
    int t0 = wv * 6, t1 = t0 + 6; if (t1 > 23) t1 = 23;
#pragma unroll 1
    for (int t = t0; t < t1; ++t) {
        int px0 = t * 16;
        int pxa = px0 + l15; if (pxa > 360) pxa = 360;   // A-row clamp; dead rows masked at D
        int oh = pxa / 19, ow = pxa % 19;
        f32x4 a0 = (f32x4){0.f, 0.f, 0.f, 0.f};
        f32x4 a1 = (f32x4){0.f, 0.f, 0.f, 0.f};
#pragma unroll
        for (int ks = 0; ks < 7; ++ks) {
            int k0 = ks * 32 + quad * 8;
            int tap = k0 / 24, ic0 = k0 - tap * 24;
            int kh = tap / 3, kw = tap - kh * 3;
            int ih = oh * 2 - 1 + kh, iw = ow * 2 - 1 + kw;
            bool val = (tap < 9) && ((unsigned)ih < 38u) && ((unsigned)iw < 38u);
            int aoff = val ? ((ih * 38 + iw) * 24 + ic0) : 34656;
            h16x8 af = *(const h16x8*)&yL[aoff];
            h16x8 w0 = *(const h16x8*)&wf[ks * 512 + quad * 128 + l15 * 8];
            h16x8 w1 = *(const h16x8*)&wf[3584 + ks * 512 + quad * 128 + l15 * 8];
            a0 = __builtin_amdgcn_mfma_f32_16x16x32_f16(af, w0, a0, 0, 0, 0);
            a1 = __builtin_amdgcn_mfma_f32_16x16x32_f16(af, w1, a1, 0, 0, 0);
        }
#pragma unroll
        for (int v = 0; v < 4; ++v) {
            int p = px0 + quad * 4 + v;                  // <= 367 < 369: unconditional LDS ok
            bool pv = p < 361;
            float x0 = relu_f(a0[v] + bb0);
            float x1 = relu_f(a1[v] + bb1);
            outL[l15 * 369 + p] = x0;
            if (l15 < 8) outL[(16 + l15) * 369 + p] = x1;
            if (pv) {
                s0 += x0; q0 += x0 * x0;
                if (l15 < 8) { s1 += x1; q1 += x1 * x1; }
            }
        }
    }
    // stats: reduce over quads (lanes sharing l15)
    s0 += __shfl_xor(s0, 16); s0 += __shfl_xor(s0, 32);
    q0 += __shfl_xor(q0, 16); q0 += __shfl_xor(q0, 32);
    s1 += __shfl_xor(s1, 16); s1 += __shfl_xor(s1, 32);
    q1 += __shfl_xor(q1, 16); q1 += __shfl_xor(q1, 32);
    if (quad == 0) {
        red[wv][l15] = s0; red[wv][24 + l15] = q0;
        if (l15 < 8) { red[wv][16 + l15] = s1; red[wv][40 + l15] = q1; }
    }
    __syncthreads();
    float* yo = yout + (long)b * 8664;
    for (int i = tid; i < 8664; i += 256) {
        int oc = i / 361, p = i - oc * 361;
        yo[i] = outL[oc * 369 + p];                      // y2 linear == (b*24+oc)*361+p
    }
    if (tid < 48)
        atomicAdd(&ostats[(blockIdx.x & 15) * 48 + tid],
                  red[0][tid] + red[1][tid] + red[2][tid] + red[3][tid]);
}

// ---------------- conv3/4: 24->24, stride2 pad1; in-BN folded; fused out-stats ------------
__global__ __launch_bounds__(256) void k_conv(const float* yin, const float* w,
                                              const float* bias, const float* instats,
                                              const float* bng, const float* bnb,
                                              float* yout, float* ostats,
                                              int Hin, int Hout, float invN) {
    __shared__ float wl[5184], bl[24], sc[24], sh[24], red[4][48];
    int tid = threadIdx.x;
    if (tid < 24) {
        float s = 0.f, s2 = 0.f;
#pragma unroll
        for (int k = 0; k < 16; ++k) { s += instats[k * 48 + tid]; s2 += instats[k * 48 + 24 + tid]; }
        float mu = s * invN;
        float var = s2 * invN - mu * mu;
        float sca = bng[tid] * rsqrtf(var + EPS);
        sc[tid] = sca; sh[tid] = bnb[tid] - mu * sca;
        bl[tid] = bias[tid];
    }
    for (int i = tid; i < 5184; i += 256) wl[i] = w[i];
    __syncthreads();
    int idx = blockIdx.x * 256 + tid;      // grids exact
    int HWo = Hout * Hout;
    int b = idx / HWo, rem = idx % HWo;
    int oh = rem / Hout, ow = rem % Hout;
    float acc[24];
#pragma unroll
    for (int o = 0; o < 24; ++o) acc[o] = bl[o];
    for (int ic = 0; ic < 24; ++ic) {
        float patch[9];
        float scc = sc[ic], shc = sh[ic];
#pragma unroll
        for (int kh = 0; kh < 3; ++kh) {
            int ih = oh * 2 - 1 + kh;
#pragma unroll
            for (int kw = 0; kw < 3; ++kw) {
                int iw = ow * 2 - 1 + kw;
                bool ok = (unsigned)ih < (unsigned)Hin && (unsigned)iw < (unsigned)Hin;
                patch[kh * 3 + kw] = ok ? yin[((b * 24 + ic) * Hin + ih) * Hin + iw] * scc + shc : 0.f;
            }
        }
#pragma unroll
        for (int o = 0; o < 24; ++o)
#pragma unroll
            for (int t = 0; t < 9; ++t) acc[o] += wl[(o * 24 + ic) * 9 + t] * patch[t];
    }
    int wave = tid >> 6;
#pragma unroll
    for (int o = 0; o < 24; ++o) {
        acc[o] = relu_f(acc[o]);
        yout[(b * 24 + o) * HWo + rem] = acc[o];
        float v = acc[o], v2 = v * v;
#pragma unroll
        for (int off = 1; off < 64; off <<= 1) { v += __shfl_xor(v, off); v2 += __shfl_xor(v2, off); }
        if ((tid & 63) == 0) { red[wave][o] = v; red[wave][24 + o] = v2; }
    }
    __syncthreads();
    if (tid < 48)
        atomicAdd(&ostats[(blockIdx.x & 15) * 48 + tid],
                  red[0][tid] + red[1][tid] + red[2][tid] + red[3][tid]);
}

// ---------------- objects: bn4 + coords once into LDS, project through split g_w1 ----------
__global__ __launch_bounds__(256) void k_obj(const float* y4, const float* qst,
                                             const float* w1, const float* b1,
                                             const float* instats, const float* bng,
                                             const float* bnb, float* A, float* Bv, float* xg) {
    int b = blockIdx.x, tid = threadIdx.x;
    __shared__ float w1l[16128];
    __shared__ float objs[25][28];
    __shared__ float sc[24], sh[24], q[11];
    xg[b * 256 + tid] = 0.f;
    for (int i = tid; i < 16128; i += 256) w1l[i] = w1[i];
    if (tid < 24) {
        float s = 0.f, s2 = 0.f;
#pragma unroll
        for (int k = 0; k < 16; ++k) { s += instats[k * 48 + tid]; s2 += instats[k * 48 + 24 + tid]; }
        float mu = s * (1.f / 12800.f);
        float var = s2 * (1.f / 12800.f) - mu * mu;
        float sca = bng[tid] * rsqrtf(var + EPS);
        sc[tid] = sca; sh[tid] = bnb[tid] - mu * sca;
    }
    if (tid < 11) q[tid] = qst[b * 11 + tid];
    __syncthreads();
    for (int i = tid; i < 600; i += 256) {
        int c = i / 25, p = i % 25;
        objs[p][c] = y4[b * 600 + i] * sc[c] + sh[c];
    }
    if (tid < 25) { objs[tid][24] = ((tid / 5) - 2) * 0.5f; objs[tid][25] = ((tid % 5) - 2) * 0.5f; }
    __syncthreads();
    float wr[63];
#pragma unroll
    for (int k = 0; k < 63; ++k) wr[k] = w1l[tid * 63 + k];
    float qdot = b1[tid];
#pragma unroll
    for (int j = 0; j < 11; ++j) qdot += wr[52 + j] * q[j];
#pragma unroll 1
    for (int p = 0; p < 25; ++p) {
        float a = 0.f, bv = qdot;
#pragma unroll
        for (int k = 0; k < 26; ++k) { a += wr[k] * objs[p][k]; bv += wr[26 + k] * objs[p][k]; }
        A[(b * 25 + p) * 256 + tid] = a;
        Bv[(b * 25 + p) * 256 + tid] = bv;
    }
}

// ---------------- fused g-MLP v4: 64-row tile, 4 waves, 4 blocks/CU, setprio ---------------
// R4 measured: 154.8us, MfmaUtil 38.9 (= exactly the 60us of MFMA work / 155us). Plateaued
// across 3 structural variants (154-165); kept as best.
__global__ __launch_bounds__(256, 4) void k_g(const float* A, const float* Bv, const half_t* whl,
                                              const float* gb2, const float* gb3,
                                              const float* gb4, float* xg) {
    __shared__ alignas(16) half_t h[64 * 264];
    __shared__ float biasL[3][256];
    int tid = threadIdx.x;
    int lb = (blockIdx.x & 7) * 640 + (blockIdx.x >> 3);   // XCD-contiguous (5120%8==0)
    int b = lb / 10, t = lb % 10;
    int r0 = t * 64;
    int rmax = 625 - r0; if (rmax > 64) rmax = 64;
    biasL[0][tid] = gb2[tid];
    biasL[1][tid] = gb3[tid];
    biasL[2][tid] = gb4[tid];
    const float* Ab = A + b * 6400;
    const float* Bb = Bv + b * 6400;
#pragma unroll
    for (int it = 0; it < 16; ++it) {
        int r = it * 4 + (tid >> 6);                       // wave-uniform row
        int rs = __builtin_amdgcn_readfirstlane(r);
        int pr = r0 + rs; if (pr > 624) pr = 624;          // clamp; masked at final sum
        int i = pr % 25, j = pr / 25;                      // scalar div/mod
        int c4 = (tid & 63) << 2;
        float4 av = *(const float4*)&Ab[i * 256 + c4];
        float4 bv = *(const float4*)&Bb[j * 256 + c4];
        h16x4 hv = {(half_t)relu_f(av.x + bv.x), (half_t)relu_f(av.y + bv.y),
                    (half_t)relu_f(av.z + bv.z), (half_t)relu_f(av.w + bv.w)};
        *(h16x4*)&h[r * 264 + c4] = hv;
    }
    __syncthreads();
    int cg = tid >> 6, lane = tid & 63;                    // 4 waves = 4 channel-groups
    int quad = lane >> 4, l15 = lane & 15;
    const half_t* hr = h + l15 * 264;                      // this lane's row base
    const half_t* Wl = whl + (cg * 4) * 8 * 512 + lane * 8;  // wave's W base (mi=0, ks=0)
#pragma unroll 1
    for (int layer = 0; layer < 3; ++layer) {
        const half_t* W = Wl + layer * 65536;
        f32x4 acc[4][4];
#pragma unroll
        for (int mi = 0; mi < 4; ++mi)
#pragma unroll
            for (int nt = 0; nt < 4; ++nt) acc[mi][nt] = (f32x4){0.f, 0.f, 0.f, 0.f};
        // prologue: ks=0 operands in flight
        h16x8 aw0 = *(const h16x8*)&W[0 * 4096];
        h16x8 aw1 = *(const h16x8*)&W[1 * 4096];
        h16x8 aw2 = *(const h16x8*)&W[2 * 4096];
        h16x8 aw3 = *(const h16x8*)&W[3 * 4096];
        h16x8 bh0 = *(const h16x8*)&hr[0 * 4224 + quad * 8];
        h16x8 bh1 = *(const h16x8*)&hr[1 * 4224 + quad * 8];
#pragma unroll 2
        for (int ks = 0; ks < 8; ++ks) {
            int ko = ks * 32 + quad * 8;
            int ksn = (ks + 1) & 7;                 // wrap: harmless redundant load at ks=7
            int kon = ksn * 32 + quad * 8;
            // this-iter second half (covered by nt=0,1 MFMA burst):
            h16x8 bh2 = *(const h16x8*)&hr[2 * 4224 + ko];
            h16x8 bh3 = *(const h16x8*)&hr[3 * 4224 + ko];
            // next-iter W (covered by full 16-MFMA burst):
            h16x8 an0 = *(const h16x8*)&W[0 * 4096 + ksn * 512];
            h16x8 an1 = *(const h16x8*)&W[1 * 4096 + ksn * 512];
            h16x8 an2 = *(const h16x8*)&W[2 * 4096 + ksn * 512];
            h16x8 an3 = *(const h16x8*)&W[3 * 4096 + ksn * 512];
            __builtin_amdgcn_s_setprio(1);
            acc[0][0] = __builtin_amdgcn_mfma_f32_16x16x32_f16(aw0, bh0, acc[0][0], 0, 0, 0);
            acc[1][0] = __builtin_amdgcn_mfma_f32_16x16x32_f16(aw1, bh0, acc[1][0], 0, 0, 0);
            acc[2][0] = __builtin_amdgcn_mfma_f32_16x16x32_f16(aw2, bh0, acc[2][0], 0, 0, 0);
            acc[3][0] = __builtin_amdgcn_mfma_f32_16x16x32_f16(aw3, bh0, acc[3][0], 0, 0, 0);
            acc[0][1] = __builtin_amdgcn_mfma_f32_16x16x32_f16(aw0, bh1, acc[0][1], 0, 0, 0);
            acc[1][1] = __builtin_amdgcn_mfma_f32_16x16x32_f16(aw1, bh1, acc[1][1], 0, 0, 0);
            acc[2][1] = __builtin_amdgcn_mfma_f32_16x16x32_f16(aw2, bh1, acc[2][1], 0, 0, 0);
            acc[3][1] = __builtin_amdgcn_mfma_f32_16x16x32_f16(aw3, bh1, acc[3][1], 0, 0, 0);
            // next-iter first half (covered by nt=2,3 MFMA burst):
            h16x8 bn0 = *(const h16x8*)&hr[0 * 4224 + kon];
            h16x8 bn1 = *(const h16x8*)&hr[1 * 4224 + kon];
            acc[0][2] = __builtin_amdgcn_mfma_f32_16x16x32_f16(aw0, bh2, acc[0][2], 0, 0, 0);
            acc[1][2] = __builtin_amdgcn_mfma_f32_16x16x32_f16(aw1, bh2, acc[1][2], 0, 0, 0);
            acc[2][2] = __builtin_amdgcn_mfma_f32_16x16x32_f16(aw2, bh2, acc[2][2], 0, 0, 0);
            acc[3][2] = __builtin_amdgcn_mfma_f32_16x16x32_f16(aw3, bh2, acc[3][2], 0, 0, 0);
            acc[0][3] = __builtin_amdgcn_mfma_f32_16x16x32_f16(aw0, bh3, acc[0][3], 0, 0, 0);
            acc[1][3] = __builtin_amdgcn_mfma_f32_16x16x32_f16(aw1, bh3, acc[1][3], 0, 0, 0);
            acc[2][3] = __builtin_amdgcn_mfma_f32_16x16x32_f16(aw2, bh3, acc[2][3], 0, 0, 0);
            acc[3][3] = __builtin_amdgcn_mfma_f32_16x16x32_f16(aw3, bh3, acc[3][3], 0, 0, 0);
            __builtin_amdgcn_s_setprio(0);
            aw0 = an0; aw1 = an1; aw2 = an2; aw3 = an3;
            bh0 = bn0; bh1 = bn1;
        }
        __syncthreads();   // all reads of h done; safe to overwrite
        if (layer < 2) {
#pragma unroll
            for (int mi = 0; mi < 4; ++mi) {
                int c0 = cg * 64 + mi * 16 + quad * 4;
#pragma unroll
                for (int nt = 0; nt < 4; ++nt) {
                    int row = nt * 16 + l15;
                    h16x4 hv;
#pragma unroll
                    for (int v = 0; v < 4; ++v)
                        hv[v] = (half_t)relu_f(acc[mi][nt][v] + biasL[layer][c0 + v]);
                    *(h16x4*)&h[row * 264 + c0] = hv;
                }
            }
            __syncthreads();
        } else {
#pragma unroll
            for (int mi = 0; mi < 4; ++mi) {
                int c0 = cg * 64 + mi * 16 + quad * 4;
#pragma unroll
                for (int v = 0; v < 4; ++v) {
                    float s = 0.f;
#pragma unroll
                    for (int nt = 0; nt < 4; ++nt) {
                        int row = nt * 16 + l15;
                        float x = relu_f(acc[mi][nt][v] + biasL[2][c0 + v]);
                        if (row < rmax) s += x;
                    }
                    s += __shfl_xor(s, 1);
                    s += __shfl_xor(s, 2);
                    s += __shfl_xor(s, 4);
                    s += __shfl_xor(s, 8);
                    if (l15 == 0) atomicAdd(&xg[b * 256 + c0 + v], s);
                }
            }
        }
    }
}

// ---------------- f-MLP + log_softmax (2 batches per block) ----------------
__global__ __launch_bounds__(256) void k_f(const float* xg, const float* fw1, const float* fb1,
                                           const float* fw2, const float* fb2,
                                           const float* fw3, const float* fb3, float* out) {
    int b0 = blockIdx.x * 2, tid = threadIdx.x;
    __shared__ float xb[2][256], h1[2][256], l10[2][10], red[2];
    xb[0][tid] = xg[b0 * 256 + tid];
    xb[1][tid] = xg[(b0 + 1) * 256 + tid];
    __syncthreads();
    float s0 = fb1[tid], s1 = s0;
    {
        const float4* wr = (const float4*)&fw1[tid * 256];
        const float4* x0 = (const float4*)xb[0];
        const float4* x1 = (const float4*)xb[1];
#pragma unroll 8
        for (int k = 0; k < 64; ++k) {
            float4 w = wr[k], a = x0[k], c = x1[k];
            s0 += w.x * a.x + w.y * a.y + w.z * a.z + w.w * a.w;
            s1 += w.x * c.x + w.y * c.y + w.z * c.z + w.w * c.w;
        }
    }
    h1[0][tid] = relu_f(s0);
    h1[1][tid] = relu_f(s1);
    __syncthreads();
    s0 = fb2[tid]; s1 = s0;
    {
        const float4* wr = (const float4*)&fw2[tid * 256];
        const float4* x0 = (const float4*)h1[0];
        const float4* x1 = (const float4*)h1[1];
#pragma unroll 8
        for (int k = 0; k < 64; ++k) {
            float4 w = wr[k], a = x0[k], c = x1[k];
            s0 += w.x * a.x + w.y * a.y + w.z * a.z + w.w * a.w;
            s1 += w.x * c.x + w.y * c.y + w.z * c.z + w.w * c.w;
        }
    }
    __syncthreads();
    xb[0][tid] = relu_f(s0);
    xb[1][tid] = relu_f(s1);
    __syncthreads();
    if (tid < 20) {
        int bb = tid / 10, o = tid % 10;
        float v = fb3[o];
        const float4* wr = (const float4*)&fw3[o * 256];
        const float4* hv = (const float4*)xb[bb];
#pragma unroll 8
        for (int k = 0; k < 64; ++k) {
            float4 w = wr[k], x = hv[k];
            v += w.x * x.x + w.y * x.y + w.z * x.z + w.w * x.w;
        }
        l10[bb][o] = v;
    }
    __syncthreads();
    if (tid < 2) {
        float m = l10[tid][0];
        for (int i = 1; i < 10; ++i) m = fmaxf(m, l10[tid][i]);
        float e = 0.f;
        for (int i = 0; i < 10; ++i) e += expf(l10[tid][i] - m);
        red[tid] = m + logf(e);
    }
    __syncthreads();
    if (tid < 20) {
        int bb = tid / 10, o = tid % 10;
        out[(b0 + bb) * 10 + o] = l10[bb][o] - red[bb];
    }
}

extern "C" void kernel_launch(void* const* d_in, const int* in_sizes, int n_in,
                              void* d_out, int out_size, void* d_ws, size_t ws_size,
                              hipStream_t stream) {
    const float* img = (const float*)d_in[0];
    const float* qst = (const float*)d_in[1];
    const float* cw[4] = {(const float*)d_in[2], (const float*)d_in[6],
                          (const float*)d_in[10], (const float*)d_in[14]};
    const float* cb[4] = {(const float*)d_in[3], (const float*)d_in[7],
                          (const float*)d_in[11], (const float*)d_in[15]};
    const float* bg[4] = {(const float*)d_in[4], (const float*)d_in[8],
                          (const float*)d_in[12], (const float*)d_in[16]};
    const float* bb[4] = {(const float*)d_in[5], (const float*)d_in[9],
                          (const float*)d_in[13], (const float*)d_in[17]};
    const float* gw1 = (const float*)d_in[18];
    const float* gb1 = (const float*)d_in[19];
    const float* gw2 = (const float*)d_in[20];
    const float* gb2 = (const float*)d_in[21];
    const float* gw3 = (const float*)d_in[22];
    const float* gb3 = (const float*)d_in[23];
    const float* gw4 = (const float*)d_in[24];
    const float* gb4 = (const float*)d_in[25];
    const float* fw1 = (const float*)d_in[26];
    const float* fb1 = (const float*)d_in[27];
    const float* fw2 = (const float*)d_in[28];
    const float* fb2 = (const float*)d_in[29];
    const float* fw3 = (const float*)d_in[30];
    const float* fb3 = (const float*)d_in[31];

    float* ws = (float*)d_ws;
    half_t* y1 = (half_t*)(ws + OFF_Y1);   // f16 intermediate, [img][pix][24ch]
    float* y2 = ws + OFF_Y2;
    float* y3 = ws + OFF_Y3;
    float* y4 = ws + OFF_Y4;
    float* st = ws + OFF_ST;            // 4 layers * 16 slots * 48
    half_t* whl = (half_t*)(ws + OFF_WHL);
    half_t* whl2 = (half_t*)(ws + OFF_WHL2);  // conv2 B-frags (free hole after y1-f16)
    float* A = ws + OFF_A;              // aliases y1 (dead after conv2)
    float* Bv = ws + OFF_BV;
    float* xg = ws + OFF_XG;
    float* out = (float*)d_out;

    k_prep<<<768, 256, 0, stream>>>(gw2, gw3, gw4, whl, st);
    k_prep2<<<28, 256, 0, stream>>>(cw[1], whl2);
    k_conv1<<<1444, 256, 0, stream>>>(img, cw[0], cb[0], y1, st + 0 * 768);
    k_conv2<<<512, 256, 0, stream>>>(y1, whl2, cb[1], st + 0 * 768, bg[0], bb[0], y2,
                                     st + 1 * 768);
    k_conv<<<200, 256, 0, stream>>>(y2, cw[2], cb[2], st + 1 * 768, bg[1], bb[1], y3,
                                    st + 2 * 768, 19, 10, 1.f / 184832.f);
    k_conv<<<50, 256, 0, stream>>>(y3, cw[3], cb[3], st + 2 * 768, bg[2], bb[2], y4,
                                   st + 3 * 768, 10, 5, 1.f / 51200.f);
    k_obj<<<512, 256, 0, stream>>>(y4, qst, gw1, gb1, st + 3 * 768, bg[3], bb[3], A, Bv, xg);
    k_g<<<5120, 256, 0, stream>>>(A, Bv, whl, gb2, gb3, gb4, xg);
    k_f<<<256, 256, 0, stream>>>(xg, fw1, fb1, fw2, fb2, fw3, fb3, out);
}

// Round 8
// 517.416 us; speedup vs baseline: 4.1655x; 1.0083x over previous
//
#include <hip/hip_runtime.h>
#include <hip/hip_bf16.h>

#define EPS 1e-5f

typedef _Float16 half_t;
typedef __attribute__((ext_vector_type(8))) _Float16 h16x8;
typedef __attribute__((ext_vector_type(4))) _Float16 h16x4;
typedef __attribute__((ext_vector_type(4))) float f32x4;

__device__ __forceinline__ float relu_f(float x) { return x > 0.f ? x : 0.f; }

// ---------------- workspace layout (float units) ----------------
#define OFF_Y1   0
#define OFF_Y2   17743872
#define OFF_Y3   22179840
#define OFF_Y4   23408640
#define OFF_ST   23715840
#define OFF_WHL  23718912
// aliases inside y1 region (y1 dead after conv2):
#define OFF_A    0
#define OFF_BV   3276800
#define OFF_XG   6553600
// free hole: y1 as f16 uses only floats [0, 8871936) of its legacy region:
#define OFF_WHL2 8871936

// ---------------- prep: zero stats + cast g_w2..4 to f16, swizzled to A-frag lane order ----
// o = (mtile*8+ks)*512 + quad*128 + l15*8 + j  -> wave reads 1KB contiguous per (mtile,ks).
__global__ __launch_bounds__(256) void k_prep(const float* w2, const float* w3,
                                              const float* w4, half_t* whl, float* stats) {
    int idx = blockIdx.x * 256 + threadIdx.x;     // grid exact: 768*256 = 3*65536
    if (idx < 3072) stats[idx] = 0.f;
    int l = idx >> 16, e = idx & 65535;
    const float* w = (l == 0) ? w2 : (l == 1) ? w3 : w4;
    float v = w[e];
    int c = e >> 8, k = e & 255;
    int o = ((c >> 4) * 8 + (k >> 5)) * 512 + ((k >> 3) & 3) * 128 + (c & 15) * 8 + (k & 7);
    whl[l * 65536 + o] = (half_t)v;
}

// ---------------- prep2: conv2 weights -> B-frag layout (K=tap*24+ic pad 224, oc pad 32) ---
// offset(ntile,ks,quad,l15,j) = (ntile*7+ks)*512 + quad*128 + l15*8 + j; k=ks*32+quad*8+j.
__global__ __launch_bounds__(256) void k_prep2(const float* w2, half_t* whl2) {
    int idx = blockIdx.x * 256 + threadIdx.x;     // 28*256 = 7168 exact
    int ntile = idx / 3584, r = idx % 3584;
    int ks = r / 512, w = r % 512;
    int quad = w / 128, l15 = (w >> 3) & 15, j = w & 7;
    int k = ks * 32 + quad * 8 + j;
    int oc = ntile * 16 + l15;
    float v = 0.f;
    if (k < 216 && oc < 24) {
        int tap = k / 24, ic = k % 24;
        v = w2[(oc * 24 + ic) * 9 + tap];
    }
    whl2[idx] = (half_t)v;
}

// ---------------- conv1: 3->24 ch, 75->38, stride2 pad1, 2 images/thread ------------------
// R4: y1 layout [img][pixel(1444)][ch(24)] f16 (channel-inner) so stores are 3x h16x8 (16B)
// per image instead of 24 scalar 2B stores (G13).
__global__ __launch_bounds__(256, 2) void k_conv1(const float* img, const float* w,
                                                  const float* bias, half_t* y1, float* ostats) {
    __shared__ float wl[648], bl[24], red[4][48];
    int tid = threadIdx.x;
    if (tid < 24) bl[tid] = bias[tid];
    for (int i = tid; i < 648; i += 256) wl[i] = w[i];
    __syncthreads();
    int idx = blockIdx.x * 256 + tid;      // 1444*256 = 256*1444 exact (image-pairs)
    int b2 = idx / 1444, rem = idx % 1444;
    int b0 = b2 * 2;
    int oh = rem / 38, ow = rem % 38;
    float acc0[24], acc1[24];
#pragma unroll
    for (int o = 0; o < 24; ++o) { acc0[o] = bl[o]; acc1[o] = bl[o]; }
    for (int ic = 0; ic < 3; ++ic) {
        float p0[9], p1[9];
#pragma unroll
        for (int kh = 0; kh < 3; ++kh) {
            int ih = oh * 2 - 1 + kh;
#pragma unroll
            for (int kw = 0; kw < 3; ++kw) {
                int iw = ow * 2 - 1 + kw;
                bool ok = (unsigned)ih < 75u && (unsigned)iw < 75u;
                p0[kh * 3 + kw] = ok ? img[((b0 * 3 + ic) * 75 + ih) * 75 + iw] : 0.f;
                p1[kh * 3 + kw] = ok ? img[(((b0 + 1) * 3 + ic) * 75 + ih) * 75 + iw] : 0.f;
            }
        }
#pragma unroll
        for (int o = 0; o < 24; ++o)
#pragma unroll
            for (int t = 0; t < 9; ++t) {
                float wv = wl[(o * 3 + ic) * 9 + t];
                acc0[o] += wv * p0[t];
                acc1[o] += wv * p1[t];
            }
    }
#pragma unroll
    for (int o = 0; o < 24; ++o) { acc0[o] = relu_f(acc0[o]); acc1[o] = relu_f(acc1[o]); }
#pragma unroll
    for (int g = 0; g < 3; ++g) {
        h16x8 a, c;
#pragma unroll
        for (int j = 0; j < 8; ++j) { a[j] = (half_t)acc0[g * 8 + j]; c[j] = (half_t)acc1[g * 8 + j]; }
        *(h16x8*)&y1[((long)(b0) * 1444 + rem) * 24 + g * 8] = a;
        *(h16x8*)&y1[((long)(b0 + 1) * 1444 + rem) * 24 + g * 8] = c;
    }
    int wave = tid >> 6;
#pragma unroll
    for (int o = 0; o < 24; ++o) {
        float v = acc0[o] + acc1[o];
        float v2 = acc0[o] * acc0[o] + acc1[o] * acc1[o];
#pragma unroll
        for (int off = 1; off < 64; off <<= 1) { v += __shfl_xor(v, off); v2 += __shfl_xor(v2, off); }
        if ((tid & 63) == 0) { red[wave][o] = v; red[wave][24 + o] = v2; }
    }
    __syncthreads();
    if (tid < 48)
        atomicAdd(&ostats[(blockIdx.x & 15) * 48 + tid],
                  red[0][tid] + red[1][tid] + red[2][tid] + red[3][tid]);
}

// ---------------- conv2 v3: MFMA im2col GEMM, 1 image/block (R6, 86us -> ~25us) ------------
__global__ __launch_bounds__(256) void k_conv2(const half_t* yin, const half_t* whl2,
                                               const float* bias, const float* instats,
                                               const float* bng, const float* bnb,
                                               float* yout, float* ostats) {
    __shared__ half_t yL[34672];          // 38*38*24 + zero slot @34656
    __shared__ half_t wf[7168];
    __shared__ float outL[8856];          // 24 x stride 369
    __shared__ float scs[24], shs[24], bl[24], red[4][48];
    int tid = threadIdx.x;
    int b = blockIdx.x;
    if (tid < 24) {
        float s = 0.f, s2 = 0.f;
#pragma unroll
        for (int k = 0; k < 16; ++k) { s += instats[k * 48 + tid]; s2 += instats[k * 48 + 24 + tid]; }
        float mu = s * (1.f / 739328.f);
        float var = s2 * (1.f / 739328.f) - mu * mu;
        float sca = bng[tid] * rsqrtf(var + EPS);
        scs[tid] = sca; shs[tid] = bnb[tid] - mu * sca;
        bl[tid] = bias[tid];
    }
    if (tid < 16) yL[34656 + tid] = (half_t)0.f;   // zero slot (+pad)
    for (int i = tid; i < 896; i += 256)
        ((h16x8*)wf)[i] = ((const h16x8*)whl2)[i];
    __syncthreads();
    // stage image with input-BN applied (channels per 8-chunk never wrap: 24 = 3*8)
    const half_t* ybase = yin + (long)b * 34656;
    for (int i = tid; i < 4332; i += 256) {
        h16x8 v = *(const h16x8*)&ybase[i * 8];
        int ch0 = (i % 3) * 8;
        h16x8 o;
#pragma unroll
        for (int j = 0; j < 8; ++j)
            o[j] = (half_t)((float)v[j] * scs[ch0 + j] + shs[ch0 + j]);
        *(h16x8*)&yL[i * 8] = o;
    }
    __syncthreads();
    int wv = tid >> 6, lane = tid & 63, quad = lane >> 4, l15 = lane & 15;
    float bb0 = bl[l15];
    float bb1 = (l15 < 8) ? bl[16 + l15] : 0.f;
    float s0 = 0.f, q0 = 0.f, s1 = 0.f, q1 = 0.f;
    int t0 = wv * 6, t1 = t0 + 6; if (t1 > 23) t1 = 23;
#pragma unroll 1
    for (int t = t0; t < t1; ++t) {
        int px0 = t * 16;
        int pxa = px0 + l15; if (pxa > 360) pxa = 360;   // A-row clamp; dead rows masked at D
        int oh = pxa / 19, ow = pxa % 19;
        f32x4 a0 = (f32x4){0.f, 0.f, 0.f, 0.f};
        f32x4 a1 = (f32x4){0.f, 0.f, 0.f, 0.f};
#pragma unroll
        for (int ks = 0; ks < 7; ++ks) {
            int k0 = ks * 32 + quad * 8;
            int tap = k0 / 24, ic0 = k0 - tap * 24;
            int kh = tap / 3, kw = tap - kh * 3;
            int ih = oh * 2 - 1 + kh, iw = ow * 2 - 1 + kw;
            bool val = (tap < 9) && ((unsigned)ih < 38u) && ((unsigned)iw < 38u);
            int aoff = val ? ((ih * 38 + iw) * 24 + ic0) : 34656;
            h16x8 af = *(const h16x8*)&yL[aoff];
            h16x8 w0 = *(const h16x8*)&wf[ks * 512 + quad * 128 + l15 * 8];
            h16x8 w1 = *(const h16x8*)&wf[3584 + ks * 512 + quad * 128 + l15 * 8];
            a0 = __builtin_amdgcn_mfma_f32_16x16x32_f16(af, w0, a0, 0, 0, 0);
            a1 = __builtin_amdgcn_mfma_f32_16x16x32_f16(af, w1, a1, 0, 0, 0);
        }
#pragma unroll
        for (int v = 0; v < 4; ++v) {
            int p = px0 + quad * 4 + v;                  // <= 367 < 369: unconditional LDS ok
            bool pv = p < 361;
            float x0 = relu_f(a0[v] + bb0);
            float x1 = relu_f(a1[v] + bb1);
            outL[l15 * 369 + p] = x0;
            if (l15 < 8) outL[(16 + l15) * 369 + p] = x1;
            if (pv) {
                s0 += x0; q0 += x0 * x0;
                if (l15 < 8) { s1 += x1; q1 += x1 * x1; }
            }
        }
    }
    // stats: reduce over quads (lanes sharing l15)
    s0 += __shfl_xor(s0, 16); s0 += __shfl_xor(s0, 32);
    q0 += __shfl_xor(q0, 16); q0 += __shfl_xor(q0, 32);
    s1 += __shfl_xor(s1, 16); s1 += __shfl_xor(s1, 32);
    q1 += __shfl_xor(q1, 16); q1 += __shfl_xor(q1, 32);
    if (quad == 0) {
        red[wv][l15] = s0; red[wv][24 + l15] = q0;
        if (l15 < 8) { red[wv][16 + l15] = s1; red[wv][40 + l15] = q1; }
    }
    __syncthreads();
    float* yo = yout + (long)b * 8664;
    for (int i = tid; i < 8664; i += 256) {
        int oc = i / 361, p = i - oc * 361;
        yo[i] = outL[oc * 369 + p];                      // y2 linear == (b*24+oc)*361+p
    }
    if (tid < 48)
        atomicAdd(&ostats[(blockIdx.x & 15) * 48 + tid],
                  red[0][tid] + red[1][tid] + red[2][tid] + red[3][tid]);
}

// ---------------- conv3/4: 24->24, stride2 pad1; in-BN folded; fused out-stats ------------
__global__ __launch_bounds__(256) void k_conv(const float* yin, const float* w,
                                              const float* bias, const float* instats,
                                              const float* bng, const float* bnb,
                                              float* yout, float* ostats,
                                              int Hin, int Hout, float invN) {
    __shared__ float wl[5184], bl[24], sc[24], sh[24], red[4][48];
    int tid = threadIdx.x;
    if (tid < 24) {
        float s = 0.f, s2 = 0.f;
#pragma unroll
        for (int k = 0; k < 16; ++k) { s += instats[k * 48 + tid]; s2 += instats[k * 48 + 24 + tid]; }
        float mu = s * invN;
        float var = s2 * invN - mu * mu;
        float sca = bng[tid] * rsqrtf(var + EPS);
        sc[tid] = sca; sh[tid] = bnb[tid] - mu * sca;
        bl[tid] = bias[tid];
    }
    for (int i = tid; i < 5184; i += 256) wl[i] = w[i];
    __syncthreads();
    int idx = blockIdx.x * 256 + tid;      // grids exact
    int HWo = Hout * Hout;
    int b = idx / HWo, rem = idx % HWo;
    int oh = rem / Hout, ow = rem % Hout;
    float acc[24];
#pragma unroll
    for (int o = 0; o < 24; ++o) acc[o] = bl[o];
    for (int ic = 0; ic < 24; ++ic) {
        float patch[9];
        float scc = sc[ic], shc = sh[ic];
#pragma unroll
        for (int kh = 0; kh < 3; ++kh) {
            int ih = oh * 2 - 1 + kh;
#pragma unroll
            for (int kw = 0; kw < 3; ++kw) {
                int iw = ow * 2 - 1 + kw;
                bool ok = (unsigned)ih < (unsigned)Hin && (unsigned)iw < (unsigned)Hin;
                patch[kh * 3 + kw] = ok ? yin[((b * 24 + ic) * Hin + ih) * Hin + iw] * scc + shc : 0.f;
            }
        }
#pragma unroll
        for (int o = 0; o < 24; ++o)
#pragma unroll
            for (int t = 0; t < 9; ++t) acc[o] += wl[(o * 24 + ic) * 9 + t] * patch[t];
    }
    int wave = tid >> 6;
#pragma unroll
    for (int o = 0; o < 24; ++o) {
        acc[o] = relu_f(acc[o]);
        yout[(b * 24 + o) * HWo + rem] = acc[o];
        float v = acc[o], v2 = v * v;
#pragma unroll
        for (int off = 1; off < 64; off <<= 1) { v += __shfl_xor(v, off); v2 += __shfl_xor(v2, off); }
        if ((tid & 63) == 0) { red[wave][o] = v; red[wave][24 + o] = v2; }
    }
    __syncthreads();
    if (tid < 48)
        atomicAdd(&ostats[(blockIdx.x & 15) * 48 + tid],
                  red[0][tid] + red[1][tid] + red[2][tid] + red[3][tid]);
}

// ---------------- objects: bn4 + coords once into LDS, project through split g_w1 ----------
__global__ __launch_bounds__(256) void k_obj(const float* y4, const float* qst,
                                             const float* w1, const float* b1,
                                             const float* instats, const float* bng,
                                             const float* bnb, float* A, float* Bv, float* xg) {
    int b = blockIdx.x, tid = threadIdx.x;
    __shared__ float w1l[16128];
    __shared__ float objs[25][28];
    __shared__ float sc[24], sh[24], q[11];
    xg[b * 256 + tid] = 0.f;
    for (int i = tid; i < 16128; i += 256) w1l[i] = w1[i];
    if (tid < 24) {
        float s = 0.f, s2 = 0.f;
#pragma unroll
        for (int k = 0; k < 16; ++k) { s += instats[k * 48 + tid]; s2 += instats[k * 48 + 24 + tid]; }
        float mu = s * (1.f / 12800.f);
        float var = s2 * (1.f / 12800.f) - mu * mu;
        float sca = bng[tid] * rsqrtf(var + EPS);
        sc[tid] = sca; sh[tid] = bnb[tid] - mu * sca;
    }
    if (tid < 11) q[tid] = qst[b * 11 + tid];
    __syncthreads();
    for (int i = tid; i < 600; i += 256) {
        int c = i / 25, p = i % 25;
        objs[p][c] = y4[b * 600 + i] * sc[c] + sh[c];
    }
    if (tid < 25) { objs[tid][24] = ((tid / 5) - 2) * 0.5f; objs[tid][25] = ((tid % 5) - 2) * 0.5f; }
    __syncthreads();
    float wr[63];
#pragma unroll
    for (int k = 0; k < 63; ++k) wr[k] = w1l[tid * 63 + k];
    float qdot = b1[tid];
#pragma unroll
    for (int j = 0; j < 11; ++j) qdot += wr[52 + j] * q[j];
#pragma unroll 1
    for (int p = 0; p < 25; ++p) {
        float a = 0.f, bv = qdot;
#pragma unroll
        for (int k = 0; k < 26; ++k) { a += wr[k] * objs[p][k]; bv += wr[26 + k] * objs[p][k]; }
        A[(b * 25 + p) * 256 + tid] = a;
        Bv[(b * 25 + p) * 256 + tid] = bv;
    }
}

// ---------------- fused g-MLP v5: depth-2 W prefetch (3 rotating register sets) ------------
// R7 cycle audit: at 4 blocks/CU, 72K cyc elapsed/block vs ~7K issue-cyc/wave -> waves
// stalled ~60%; common factor across v1-v4 (all 38-40% MfmaUtil): W streamed from L2
// (~200-300cy latency) prefetched only ~100cy ahead. v5: full ks-loop unroll, W sets
// A/B/C rotate, loads issued 2 iterations (~220cy) before consumption. acc 64 + W 48 +
// bh 16 + misc ~15 = ~143 VGPR -> launch_bounds(256,3), 3 blocks/CU (12 waves/CU).
// Fail signal: MfmaUtil flat ~40 -> W-latency theory wrong, k_g at structural floor.
#define GSTEP(C0,C1,C2,C3,N0,N1,N2,N3,KS,LKS,DOLOAD) do {                                   \
    int ko = (KS) * 32 + quad * 8;                                                          \
    h16x8 b0 = *(const h16x8*)&hr[0 * 4224 + ko];                                           \
    h16x8 b1 = *(const h16x8*)&hr[1 * 4224 + ko];                                           \
    h16x8 b2 = *(const h16x8*)&hr[2 * 4224 + ko];                                           \
    h16x8 b3 = *(const h16x8*)&hr[3 * 4224 + ko];                                           \
    if (DOLOAD) {                                                                           \
        N0 = *(const h16x8*)&W[0 * 4096 + (LKS) * 512];                                     \
        N1 = *(const h16x8*)&W[1 * 4096 + (LKS) * 512];                                     \
        N2 = *(const h16x8*)&W[2 * 4096 + (LKS) * 512];                                     \
        N3 = *(const h16x8*)&W[3 * 4096 + (LKS) * 512];                                     \
    }                                                                                       \
    __builtin_amdgcn_s_setprio(1);                                                          \
    acc[0][0] = __builtin_amdgcn_mfma_f32_16x16x32_f16(C0, b0, acc[0][0], 0, 0, 0);         \
    acc[1][0] = __builtin_amdgcn_mfma_f32_16x16x32_f16(C1, b0, acc[1][0], 0, 0, 0);         \
    acc[2][0] = __builtin_amdgcn_mfma_f32_16x16x32_f16(C2, b0, acc[2][0], 0, 0, 0);         \
    acc[3][0] = __builtin_amdgcn_mfma_f32_16x16x32_f16(C3, b0, acc[3][0], 0, 0, 0);         \
    acc[0][1] = __builtin_amdgcn_mfma_f32_16x16x32_f16(C0, b1, acc[0][1], 0, 0, 0);         \
    acc[1][1] = __builtin_amdgcn_mfma_f32_16x16x32_f16(C1, b1, acc[1][1], 0, 0, 0);         \
    acc[2][1] = __builtin_amdgcn_mfma_f32_16x16x32_f16(C2, b1, acc[2][1], 0, 0, 0);         \
    acc[3][1] = __builtin_amdgcn_mfma_f32_16x16x32_f16(C3, b1, acc[3][1], 0, 0, 0);         \
    acc[0][2] = __builtin_amdgcn_mfma_f32_16x16x32_f16(C0, b2, acc[0][2], 0, 0, 0);         \
    acc[1][2] = __builtin_amdgcn_mfma_f32_16x16x32_f16(C1, b2, acc[1][2], 0, 0, 0);         \
    acc[2][2] = __builtin_amdgcn_mfma_f32_16x16x32_f16(C2, b2, acc[2][2], 0, 0, 0);         \
    acc[3][2] = __builtin_amdgcn_mfma_f32_16x16x32_f16(C3, b2, acc[3][2], 0, 0, 0);         \
    acc[0][3] = __builtin_amdgcn_mfma_f32_16x16x32_f16(C0, b3, acc[0][3], 0, 0, 0);         \
    acc[1][3] = __builtin_amdgcn_mfma_f32_16x16x32_f16(C1, b3, acc[1][3], 0, 0, 0);         \
    acc[2][3] = __builtin_amdgcn_mfma_f32_16x16x32_f16(C2, b3, acc[2][3], 0, 0, 0);         \
    acc[3][3] = __builtin_amdgcn_mfma_f32_16x16x32_f16(C3, b3, acc[3][3], 0, 0, 0);         \
    __builtin_amdgcn_s_setprio(0);                                                          \
} while (0)

__global__ __launch_bounds__(256, 3) void k_g(const float* A, const float* Bv, const half_t* whl,
                                              const float* gb2, const float* gb3,
                                              const float* gb4, float* xg) {
    __shared__ alignas(16) half_t h[64 * 264];
    __shared__ float biasL[3][256];
    int tid = threadIdx.x;
    int lb = (blockIdx.x & 7) * 640 + (blockIdx.x >> 3);   // XCD-contiguous (5120%8==0)
    int b = lb / 10, t = lb % 10;
    int r0 = t * 64;
    int rmax = 625 - r0; if (rmax > 64) rmax = 64;
    biasL[0][tid] = gb2[tid];
    biasL[1][tid] = gb3[tid];
    biasL[2][tid] = gb4[tid];
    const float* Ab = A + b * 6400;
    const float* Bb = Bv + b * 6400;
#pragma unroll
    for (int it = 0; it < 16; ++it) {
        int r = it * 4 + (tid >> 6);                       // wave-uniform row
        int rs = __builtin_amdgcn_readfirstlane(r);
        int pr = r0 + rs; if (pr > 624) pr = 624;          // clamp; masked at final sum
        int i = pr % 25, j = pr / 25;                      // scalar div/mod
        int c4 = (tid & 63) << 2;
        float4 av = *(const float4*)&Ab[i * 256 + c4];
        float4 bv = *(const float4*)&Bb[j * 256 + c4];
        h16x4 hv = {(half_t)relu_f(av.x + bv.x), (half_t)relu_f(av.y + bv.y),
                    (half_t)relu_f(av.z + bv.z), (half_t)relu_f(av.w + bv.w)};
        *(h16x4*)&h[r * 264 + c4] = hv;
    }
    __syncthreads();
    int cg = tid >> 6, lane = tid & 63;                    // 4 waves = 4 channel-groups
    int quad = lane >> 4, l15 = lane & 15;
    const half_t* hr = h + l15 * 264;                      // this lane's row base
    const half_t* Wl = whl + (cg * 4) * 8 * 512 + lane * 8;  // wave's W base (mi=0, ks=0)
#pragma unroll 1
    for (int layer = 0; layer < 3; ++layer) {
        const half_t* W = Wl + layer * 65536;
        f32x4 acc[4][4];
#pragma unroll
        for (int mi = 0; mi < 4; ++mi)
#pragma unroll
            for (int nt = 0; nt < 4; ++nt) acc[mi][nt] = (f32x4){0.f, 0.f, 0.f, 0.f};
        // prologue: W sets for ks=0 (A) and ks=1 (B) in flight
        h16x8 wA0 = *(const h16x8*)&W[0 * 4096];
        h16x8 wA1 = *(const h16x8*)&W[1 * 4096];
        h16x8 wA2 = *(const h16x8*)&W[2 * 4096];
        h16x8 wA3 = *(const h16x8*)&W[3 * 4096];
        h16x8 wB0 = *(const h16x8*)&W[0 * 4096 + 512];
        h16x8 wB1 = *(const h16x8*)&W[1 * 4096 + 512];
        h16x8 wB2 = *(const h16x8*)&W[2 * 4096 + 512];
        h16x8 wB3 = *(const h16x8*)&W[3 * 4096 + 512];
        h16x8 wC0, wC1, wC2, wC3;
        GSTEP(wA0, wA1, wA2, wA3, wC0, wC1, wC2, wC3, 0, 2, 1);
        GSTEP(wB0, wB1, wB2, wB3, wA0, wA1, wA2, wA3, 1, 3, 1);
        GSTEP(wC0, wC1, wC2, wC3, wB0, wB1, wB2, wB3, 2, 4, 1);
        GSTEP(wA0, wA1, wA2, wA3, wC0, wC1, wC2, wC3, 3, 5, 1);
        GSTEP(wB0, wB1, wB2, wB3, wA0, wA1, wA2, wA3, 4, 6, 1);
        GSTEP(wC0, wC1, wC2, wC3, wB0, wB1, wB2, wB3, 5, 7, 1);
        GSTEP(wA0, wA1, wA2, wA3, wA0, wA1, wA2, wA3, 6, 0, 0);
        GSTEP(wB0, wB1, wB2, wB3, wB0, wB1, wB2, wB3, 7, 0, 0);
        __syncthreads();   // all reads of h done; safe to overwrite
        if (layer < 2) {
#pragma unroll
            for (int mi = 0; mi < 4; ++mi) {
                int c0 = cg * 64 + mi * 16 + quad * 4;
#pragma unroll
                for (int nt = 0; nt < 4; ++nt) {
                    int row = nt * 16 + l15;
                    h16x4 hv;
#pragma unroll
                    for (int v = 0; v < 4; ++v)
                        hv[v] = (half_t)relu_f(acc[mi][nt][v] + biasL[layer][c0 + v]);
                    *(h16x4*)&h[row * 264 + c0] = hv;
                }
            }
            __syncthreads();
        } else {
#pragma unroll
            for (int mi = 0; mi < 4; ++mi) {
                int c0 = cg * 64 + mi * 16 + quad * 4;
#pragma unroll
                for (int v = 0; v < 4; ++v) {
                    float s = 0.f;
#pragma unroll
                    for (int nt = 0; nt < 4; ++nt) {
                        int row = nt * 16 + l15;
                        float x = relu_f(acc[mi][nt][v] + biasL[2][c0 + v]);
                        if (row < rmax) s += x;
                    }
                    s += __shfl_xor(s, 1);
                    s += __shfl_xor(s, 2);
                    s += __shfl_xor(s, 4);
                    s += __shfl_xor(s, 8);
                    if (l15 == 0) atomicAdd(&xg[b * 256 + c0 + v], s);
                }
            }
        }
    }
}

// ---------------- f-MLP + log_softmax (2 batches per block) ----------------
__global__ __launch_bounds__(256) void k_f(const float* xg, const float* fw1, const float* fb1,
                                           const float* fw2, const float* fb2,
                                           const float* fw3, const float* fb3, float* out) {
    int b0 = blockIdx.x * 2, tid = threadIdx.x;
    __shared__ float xb[2][256], h1[2][256], l10[2][10], red[2];
    xb[0][tid] = xg[b0 * 256 + tid];
    xb[1][tid] = xg[(b0 + 1) * 256 + tid];
    __syncthreads();
    float s0 = fb1[tid], s1 = s0;
    {
        const float4* wr = (const float4*)&fw1[tid * 256];
        const float4* x0 = (const float4*)xb[0];
        const float4* x1 = (const float4*)xb[1];
#pragma unroll 8
        for (int k = 0; k < 64; ++k) {
            float4 w = wr[k], a = x0[k], c = x1[k];
            s0 += w.x * a.x + w.y * a.y + w.z * a.z + w.w * a.w;
            s1 += w.x * c.x + w.y * c.y + w.z * c.z + w.w * c.w;
        }
    }
    h1[0][tid] = relu_f(s0);
    h1[1][tid] = relu_f(s1);
    __syncthreads();
    s0 = fb2[tid]; s1 = s0;
    {
        const float4* wr = (const float4*)&fw2[tid * 256];
        const float4* x0 = (const float4*)h1[0];
        const float4* x1 = (const float4*)h1[1];
#pragma unroll 8
        for (int k = 0; k < 64; ++k) {
            float4 w = wr[k], a = x0[k], c = x1[k];
            s0 += w.x * a.x + w.y * a.y + w.z * a.z + w.w * a.w;
            s1 += w.x * c.x + w.y * c.y + w.z * c.z + w.w * c.w;
        }
    }
    __syncthreads();
    xb[0][tid] = relu_f(s0);
    xb[1][tid] = relu_f(s1);
    __syncthreads();
    if (tid < 20) {
        int bb = tid / 10, o = tid % 10;
        float v = fb3[o];
        const float4* wr = (const float4*)&fw3[o * 256];
        const float4* hv = (const float4*)xb[bb];
#pragma unroll 8
        for (int k = 0; k < 64; ++k) {
            float4 w = wr[k], x = hv[k];
            v += w.x * x.x + w.y * x.y + w.z * x.z + w.w * x.w;
        }
        l10[bb][o] = v;
    }
    __syncthreads();
    if (tid < 2) {
        float m = l10[tid][0];
        for (int i = 1; i < 10; ++i) m = fmaxf(m, l10[tid][i]);
        float e = 0.f;
        for (int i = 0; i < 10; ++i) e += expf(l10[tid][i] - m);
        red[tid] = m + logf(e);
    }
    __syncthreads();
    if (tid < 20) {
        int bb = tid / 10, o = tid % 10;
        out[(b0 + bb) * 10 + o] = l10[bb][o] - red[bb];
    }
}

extern "C" void kernel_launch(void* const* d_in, const int* in_sizes, int n_in,
                              void* d_out, int out_size, void* d_ws, size_t ws_size,
                              hipStream_t stream) {
    const float* img = (const float*)d_in[0];
    const float* qst = (const float*)d_in[1];
    const float* cw[4] = {(const float*)d_in[2], (const float*)d_in[6],
                          (const float*)d_in[10], (const float*)d_in[14]};
    const float* cb[4] = {(const float*)d_in[3], (const float*)d_in[7],
                          (const float*)d_in[11], (const float*)d_in[15]};
    const float* bg[4] = {(const float*)d_in[4], (const float*)d_in[8],
                          (const float*)d_in[12], (const float*)d_in[16]};
    const float* bb[4] = {(const float*)d_in[5], (const float*)d_in[9],
                          (const float*)d_in[13], (const float*)d_in[17]};
    const float* gw1 = (const float*)d_in[18];
    const float* gb1 = (const float*)d_in[19];
    const float* gw2 = (const float*)d_in[20];
    const float* gb2 = (const float*)d_in[21];
    const float* gw3 = (const float*)d_in[22];
    const float* gb3 = (const float*)d_in[23];
    const float* gw4 = (const float*)d_in[24];
    const float* gb4 = (const float*)d_in[25];
    const float* fw1 = (const float*)d_in[26];
    const float* fb1 = (const float*)d_in[27];
    const float* fw2 = (const float*)d_in[28];
    const float* fb2 = (const float*)d_in[29];
    const float* fw3 = (const float*)d_in[30];
    const float* fb3 = (const float*)d_in[31];

    float* ws = (float*)d_ws;
    half_t* y1 = (half_t*)(ws + OFF_Y1);   // f16 intermediate, [img][pix][24ch]
    float* y2 = ws + OFF_Y2;
    float* y3 = ws + OFF_Y3;
    float* y4 = ws + OFF_Y4;
    float* st = ws + OFF_ST;            // 4 layers * 16 slots * 48
    half_t* whl = (half_t*)(ws + OFF_WHL);
    half_t* whl2 = (half_t*)(ws + OFF_WHL2);  // conv2 B-frags (free hole after y1-f16)
    float* A = ws + OFF_A;              // aliases y1 (dead after conv2)
    float* Bv = ws + OFF_BV;
    float* xg = ws + OFF_XG;
    float* out = (float*)d_out;

    k_prep<<<768, 256, 0, stream>>>(gw2, gw3, gw4, whl, st);
    k_prep2<<<28, 256, 0, stream>>>(cw[1], whl2);
    k_conv1<<<1444, 256, 0, stream>>>(img, cw[0], cb[0], y1, st + 0 * 768);
    k_conv2<<<512, 256, 0, stream>>>(y1, whl2, cb[1], st + 0 * 768, bg[0], bb[0], y2,
                                     st + 1 * 768);
    k_conv<<<200, 256, 0, stream>>>(y2, cw[2], cb[2], st + 1 * 768, bg[1], bb[1], y3,
                                    st + 2 * 768, 19, 10, 1.f / 184832.f);
    k_conv<<<50, 256, 0, stream>>>(y3, cw[3], cb[3], st + 2 * 768, bg[2], bb[2], y4,
                                   st + 3 * 768, 10, 5, 1.f / 51200.f);
    k_obj<<<512, 256, 0, stream>>>(y4, qst, gw1, gb1, st + 3 * 768, bg[3], bb[3], A, Bv, xg);
    k_g<<<5120, 256, 0, stream>>>(A, Bv, whl, gb2, gb3, gb4, xg);
    k_f<<<256, 256, 0, stream>>>(xg, fw1, fb1, fw2, fb2, fw3, fb3, out);
}